// Round 8
// baseline (1665.035 us; speedup 1.0000x reference)
//
#include <hip/hip_runtime.h>

typedef __bf16 bf16;
typedef bf16 bf16x4_t __attribute__((ext_vector_type(4)));
typedef bf16 bf16x8_t __attribute__((ext_vector_type(8)));
typedef float f32x4_t __attribute__((ext_vector_type(4)));

#define DI __device__ __forceinline__

DI void gload_lds16(const void* g, void* l) {
  __builtin_amdgcn_global_load_lds((const __attribute__((address_space(1))) void*)g,
                                   (__attribute__((address_space(3))) void*)l, 16, 0, 0);
}

DI f32x4_t mfma16(bf16x8_t a, bf16x8_t b, f32x4_t c) {
  return __builtin_amdgcn_mfma_f32_16x16x32_bf16(a, b, c, 0, 0, 0);
}

DI unsigned short bfbits(float f) {
  bf16 h = (bf16)f;
  return __builtin_bit_cast(unsigned short, h);
}

// ---------------- fused prep: LN (1 wave/row) + weight transposes ----------------
__global__ __launch_bounds__(256) void prep_all(const float* __restrict__ x,
                                                const float* __restrict__ lat,
                                                const float* __restrict__ g1,
                                                const float* __restrict__ b1,
                                                const float* __restrict__ g2,
                                                const float* __restrict__ b2,
                                                const float* __restrict__ Wq,
                                                const float* __restrict__ Wkv,
                                                const float* __restrict__ Wo,
                                                bf16* __restrict__ kv_in,
                                                bf16* __restrict__ lnq,
                                                bf16* __restrict__ Wq_t,
                                                bf16* __restrict__ Wkv_t,
                                                bf16* __restrict__ Wo_t) {
  const int bid = blockIdx.x;
  const int t = threadIdx.x;
  if (bid < 8320) {
    const int wv = t >> 6, l = t & 63;
    const int row = bid * 4 + wv;
    const float* in;
    const float* gamma;
    const float* beta;
    size_t orow;
    bool dual = false;
    int lrow = 0;
    if (row < 32768) {
      in = x + (size_t)row * 1024;
      gamma = g1; beta = b1;
      orow = (size_t)(row >> 12) * 4160 + (row & 4095);
    } else {
      const int r = row - 32768;
      in = lat + (size_t)r * 1024;
      gamma = g2; beta = b2;
      orow = (size_t)(r >> 6) * 4160 + 4096 + (r & 63);
      dual = true;
      lrow = r;
    }
    float4 v[4];
    float s = 0.f, q = 0.f;
#pragma unroll
    for (int i = 0; i < 4; ++i) {
      v[i] = ((const float4*)in)[i * 64 + l];
      s += v[i].x + v[i].y + v[i].z + v[i].w;
      q += v[i].x * v[i].x + v[i].y * v[i].y + v[i].z * v[i].z + v[i].w * v[i].w;
    }
#pragma unroll
    for (int off = 1; off < 64; off <<= 1) {
      s += __shfl_xor(s, off);
      q += __shfl_xor(q, off);
    }
    const float mu = s * (1.f / 1024.f);
    const float var = q * (1.f / 1024.f) - mu * mu;
    const float rs = rsqrtf(var + 1e-5f);
#pragma unroll
    for (int i = 0; i < 4; ++i) {
      const float4 gv = ((const float4*)gamma)[i * 64 + l];
      const float4 bv = ((const float4*)beta)[i * 64 + l];
      bf16x4_t o;
      o[0] = (bf16)((v[i].x - mu) * rs * gv.x + bv.x);
      o[1] = (bf16)((v[i].y - mu) * rs * gv.y + bv.y);
      o[2] = (bf16)((v[i].z - mu) * rs * gv.z + bv.z);
      o[3] = (bf16)((v[i].w - mu) * rs * gv.w + bv.w);
      *(bf16x4_t*)(kv_in + orow * 1024 + i * 256 + l * 4) = o;
      if (dual) *(bf16x4_t*)(lnq + (size_t)lrow * 1024 + i * 256 + l * 4) = o;
    }
  } else {
    __shared__ float tile[32][33];
    const int b2i = bid - 8320;
    const float* W;
    bf16* Wt;
    int C, t0;
    if (b2i < 1024)      { W = Wq;  Wt = Wq_t;  C = 1024; t0 = b2i; }
    else if (b2i < 3072) { W = Wkv; Wt = Wkv_t; C = 2048; t0 = b2i - 1024; }
    else                 { W = Wo;  Wt = Wo_t;  C = 1024; t0 = b2i - 3072; }
    const int R = 1024;
    const int ntx = C >> 5;
    const int c0 = (t0 % ntx) * 32, r0 = (t0 / ntx) * 32;
    const int tx = t & 31, ty = t >> 5;
#pragma unroll
    for (int j = 0; j < 4; ++j)
      tile[ty + j * 8][tx] = W[(size_t)(r0 + ty + j * 8) * C + c0 + tx];
    __syncthreads();
#pragma unroll
    for (int j = 0; j < 4; ++j)
      Wt[(size_t)(c0 + ty + j * 8) * R + r0 + tx] = (bf16)tile[tx][ty + j * 8];
  }
}

// ---------------- out GEMM, split-K=4, atomic f32 accumulate ----------------
// C[512,1024] += A[512,1024] x Bt[1024,1024]^T over K slice blockIdx.z*256..+256
__global__ __launch_bounds__(256) void gemm_bt_sk(const bf16* __restrict__ A,
                                                  const bf16* __restrict__ Bt,
                                                  float* __restrict__ Cf) {
  __shared__ bf16 As[128 * 32];
  __shared__ bf16 Bs[128 * 32];
  const int tid = threadIdx.x;
  const int w = tid >> 6, l = tid & 63;
  const int lg = l >> 4, lr = l & 15;
  const int m0 = blockIdx.y * 128, n0 = blockIdx.x * 128;
  const int kbase = blockIdx.z * 256;
  const int wm = w >> 1, wn = w & 1;
  const int K = 1024, N = 1024;

  f32x4_t acc[4][4];
#pragma unroll
  for (int i = 0; i < 4; ++i)
#pragma unroll
    for (int j = 0; j < 4; ++j)
      acc[i][j] = f32x4_t{0.f, 0.f, 0.f, 0.f};

  for (int kt = 0; kt < 8; ++kt) {
    const int k0 = kbase + kt * 32;
#pragma unroll
    for (int j = 0; j < 2; ++j) {
      const int rb = j * 64 + w * 16;
      const int r = rb + (l >> 2);
      const int c = (l & 3) * 8;
      gload_lds16(A + (size_t)(m0 + r) * K + k0 + c, &As[rb * 32]);
      gload_lds16(Bt + (size_t)(n0 + r) * K + k0 + c, &Bs[rb * 32]);
    }
    __syncthreads();
    bf16x8_t af[4], bfr[4];
#pragma unroll
    for (int i = 0; i < 4; ++i) {
      af[i] = *(const bf16x8_t*)&As[(wm * 64 + i * 16 + lr) * 32 + lg * 8];
      bfr[i] = *(const bf16x8_t*)&Bs[(wn * 64 + i * 16 + lr) * 32 + lg * 8];
    }
#pragma unroll
    for (int mf = 0; mf < 4; ++mf)
#pragma unroll
      for (int nf = 0; nf < 4; ++nf)
        acc[mf][nf] = mfma16(af[mf], bfr[nf], acc[mf][nf]);
    __syncthreads();
  }

#pragma unroll
  for (int mf = 0; mf < 4; ++mf)
#pragma unroll
    for (int r = 0; r < 4; ++r) {
      const int grow = m0 + wm * 64 + mf * 16 + 4 * lg + r;
#pragma unroll
      for (int nf = 0; nf < 4; ++nf) {
        const int gcol = n0 + wn * 64 + nf * 16 + lr;
        unsafeAtomicAdd(&Cf[(size_t)grow * N + gcol], acc[mf][nf][r]);
      }
    }
}

// ---------------- 256x256 GEMM, single-buffered 64KB LDS, 2 blocks/CU ----------------
// kv projection (blocks swz<1040) + q projection (8 tail blocks).
// Per K-tile: ph0 {rd A0-3,B0-1; bar; MFMA} ph1 {rd B2-3; bar; MFMA}
//             ph2 {rd A4-7; restage B(kt+1) in place (safe: ph1 bar drained all B reads); bar; MFMA}
//             ph3 {restage A(kt+1) (safe: ph2 bar drained all A reads); vmcnt(0); bar; MFMA}.
// A's prefetch cover ~0 -> per-block HBM stall, hidden by the co-resident block (2/CU).
__global__ __launch_bounds__(512, 4) void gemm256_kv(const bf16* __restrict__ Akv,
                                                     const bf16* __restrict__ Aq,
                                                     const bf16* __restrict__ BtKV,
                                                     const bf16* __restrict__ BtQ,
                                                     bf16* __restrict__ Kout,
                                                     bf16* __restrict__ Vout,
                                                     bf16* __restrict__ Qout) {
  extern __shared__ char lds[];
  const int tid = threadIdx.x;
  const int w = tid >> 6, l = tid & 63;
  const int lr = l & 15, lg = l >> 4;
  const int wr = w >> 2, wc = w & 3;

  const int cpx = gridDim.x >> 3;
  const int swz = (blockIdx.x & 7) * cpx + (blockIdx.x >> 3);
  const bool isQ = swz >= 1040;
  const bf16* Ap;
  const bf16* Bp;
  int m0, n0;
  if (!isQ) {
    m0 = (swz >> 3) << 8;
    n0 = (swz & 7) << 8;
    Ap = Akv; Bp = BtKV;
  } else {
    const int qi = swz - 1040;
    m0 = (qi >> 2) << 8;
    n0 = (qi & 3) << 8;
    Ap = Aq; Bp = BtQ;
  }

  auto stage = [&](const bf16* __restrict__ G, int row0, int k0, char* base, int half) {
#pragma unroll
    for (int j = 0; j < 2; ++j) {
      const int r0 = half * 128 + (w * 2 + j) * 8;
      const int row = r0 + (l >> 3);
      const int col = ((l & 7) ^ (l >> 3)) * 8;
      gload_lds16(G + (size_t)(row0 + row) * 1024 + k0 + col, base + r0 * 128);
    }
  };
  auto rdA = [&](char* base, int mf, int ks) -> bf16x8_t {
    const int row = wr * 128 + mf * 16 + lr;
    int byte = row * 128 + (ks * 32 + lg * 8) * 2;
    byte ^= (row & 7) << 4;
    return *(const bf16x8_t*)(base + byte);
  };
  auto rdB = [&](char* base, int nf, int ks) -> bf16x8_t {
    const int row = wc * 64 + nf * 16 + lr;
    int byte = row * 128 + (ks * 32 + lg * 8) * 2;
    byte ^= (row & 7) << 4;
    return *(const bf16x8_t*)(base + byte);
  };

  f32x4_t acc[8][4];
#pragma unroll
  for (int i = 0; i < 8; ++i)
#pragma unroll
    for (int j = 0; j < 4; ++j)
      acc[i][j] = f32x4_t{0.f, 0.f, 0.f, 0.f};

  char* Ab = lds;          // 32KB: 256 rows x 128B
  char* Bb = lds + 32768;  // 32KB

  const int NK = 16;

  // prologue: stage tile 0 fully
  stage(Ap, m0, 0, Ab, 0);
  stage(Ap, m0, 0, Ab, 1);
  stage(Bp, n0, 0, Bb, 0);
  stage(Bp, n0, 0, Bb, 1);
  asm volatile("s_waitcnt vmcnt(0)" ::: "memory");
  __builtin_amdgcn_s_barrier();

  bf16x8_t ra[4][2], rb[4][2];
  for (int kt = 0; kt < NK; ++kt) {
    const int k1 = (kt + 1) << 6;

    // ---- phase 0: read A mf0-3, B nf0-1; bar; MFMA
#pragma unroll
    for (int mf = 0; mf < 4; ++mf) { ra[mf][0] = rdA(Ab, mf, 0); ra[mf][1] = rdA(Ab, mf, 1); }
#pragma unroll
    for (int nf = 0; nf < 2; ++nf) { rb[nf][0] = rdB(Bb, nf, 0); rb[nf][1] = rdB(Bb, nf, 1); }
    asm volatile("s_waitcnt lgkmcnt(0)" ::: "memory");
    __builtin_amdgcn_sched_barrier(0);
    __builtin_amdgcn_s_barrier();
    __builtin_amdgcn_s_setprio(1);
#pragma unroll
    for (int mf = 0; mf < 4; ++mf)
#pragma unroll
      for (int nf = 0; nf < 2; ++nf) {
        acc[mf][nf] = mfma16(ra[mf][0], rb[nf][0], acc[mf][nf]);
        acc[mf][nf] = mfma16(ra[mf][1], rb[nf][1], acc[mf][nf]);
      }
    __builtin_amdgcn_s_setprio(0);

    // ---- phase 1: read B nf2-3; bar; MFMA  (after this bar ALL B reads are drained)
#pragma unroll
    for (int nf = 2; nf < 4; ++nf) { rb[nf][0] = rdB(Bb, nf, 0); rb[nf][1] = rdB(Bb, nf, 1); }
    asm volatile("s_waitcnt lgkmcnt(0)" ::: "memory");
    __builtin_amdgcn_sched_barrier(0);
    __builtin_amdgcn_s_barrier();
    __builtin_amdgcn_s_setprio(1);
#pragma unroll
    for (int mf = 0; mf < 4; ++mf)
#pragma unroll
      for (int nf = 2; nf < 4; ++nf) {
        acc[mf][nf] = mfma16(ra[mf][0], rb[nf][0], acc[mf][nf]);
        acc[mf][nf] = mfma16(ra[mf][1], rb[nf][1], acc[mf][nf]);
      }
    __builtin_amdgcn_s_setprio(0);

    // ---- phase 2: read A mf4-7; restage B(kt+1) in place; bar; MFMA
#pragma unroll
    for (int mf = 0; mf < 4; ++mf) { ra[mf][0] = rdA(Ab, mf + 4, 0); ra[mf][1] = rdA(Ab, mf + 4, 1); }
    if (kt + 1 < NK) { stage(Bp, n0, k1, Bb, 0); stage(Bp, n0, k1, Bb, 1); }
    asm volatile("s_waitcnt lgkmcnt(0)" ::: "memory");
    __builtin_amdgcn_sched_barrier(0);
    __builtin_amdgcn_s_barrier();
    __builtin_amdgcn_s_setprio(1);
#pragma unroll
    for (int mf = 0; mf < 4; ++mf)
#pragma unroll
      for (int nf = 0; nf < 2; ++nf) {
        acc[mf + 4][nf] = mfma16(ra[mf][0], rb[nf][0], acc[mf + 4][nf]);
        acc[mf + 4][nf] = mfma16(ra[mf][1], rb[nf][1], acc[mf + 4][nf]);
      }
    __builtin_amdgcn_s_setprio(0);

    // ---- phase 3: restage A(kt+1) in place; vmcnt(0); bar; MFMA
    if (kt + 1 < NK) { stage(Ap, m0, k1, Ab, 0); stage(Ap, m0, k1, Ab, 1); }
    asm volatile("s_waitcnt vmcnt(0)" ::: "memory");
    __builtin_amdgcn_sched_barrier(0);
    __builtin_amdgcn_s_barrier();
    __builtin_amdgcn_s_setprio(1);
#pragma unroll
    for (int mf = 0; mf < 4; ++mf)
#pragma unroll
      for (int nf = 2; nf < 4; ++nf) {
        acc[mf + 4][nf] = mfma16(ra[mf][0], rb[nf][0], acc[mf + 4][nf]);
        acc[mf + 4][nf] = mfma16(ra[mf][1], rb[nf][1], acc[mf + 4][nf]);
      }
    __builtin_amdgcn_s_setprio(0);
  }

  if (isQ) {
#pragma unroll
    for (int mf = 0; mf < 8; ++mf) {
      const int grow0 = m0 + wr * 128 + mf * 16 + 4 * lg;
#pragma unroll
      for (int nf = 0; nf < 4; ++nf) {
        const int gcol = n0 + wc * 64 + nf * 16 + lr;
        const int h = gcol >> 6, d = gcol & 63;
#pragma unroll
        for (int r = 0; r < 4; ++r) {
          const int grow = grow0 + r;
          const int b = grow >> 6, i = grow & 63;
          Qout[((size_t)((b * 16 + h) * 64 + i)) * 64 + d] = (bf16)acc[mf][nf][r];
        }
      }
    }
    return;
  }
#pragma unroll
  for (int mf = 0; mf < 8; ++mf) {
    const int grow0 = m0 + wr * 128 + mf * 16 + 4 * lg;
#pragma unroll
    for (int nf = 0; nf < 4; ++nf) {
      const int gcol = n0 + wc * 64 + nf * 16 + lr;
      if (gcol < 1024) {
        const int h = gcol >> 6, d = gcol & 63;
#pragma unroll
        for (int r = 0; r < 4; ++r) {
          const int grow = grow0 + r;
          const int bb = grow / 4160, s = grow % 4160;
          Kout[((size_t)((bb * 16 + h) * 4160 + s)) * 64 + d] = (bf16)acc[mf][nf][r];
        }
      } else {
        const int c2 = gcol - 1024, h = c2 >> 6, d = c2 & 63;
        const int bb = grow0 / 4160, s0 = grow0 % 4160;
        ushort4 u;
        u.x = bfbits(acc[mf][nf][0]);
        u.y = bfbits(acc[mf][nf][1]);
        u.z = bfbits(acc[mf][nf][2]);
        u.w = bfbits(acc[mf][nf][3]);
        *(ushort4*)&Vout[((size_t)((bb * 16 + h) * 64 + d)) * 4160 + s0] = u;
      }
    }
  }
}

// ---------------- flash attention partials: 4 independent waves/WG, 5 kv-chunks ----------------
__global__ __launch_bounds__(256) void attn_part(const bf16* __restrict__ qb_,
                                                 const bf16* __restrict__ kb_,
                                                 const bf16* __restrict__ vb_,
                                                 float* __restrict__ ob,
                                                 float* __restrict__ mb,
                                                 float* __restrict__ lb) {
  const int c = blockIdx.x;   // 0..4
  const int bh = blockIdx.y;  // 0..127
  const int tid = threadIdx.x;
  const int wave = tid >> 6, l = tid & 63;
  const int lg = l >> 4, lr = l & 15;
  const int qr0 = wave * 16;

  const bf16* q = qb_ + ((size_t)bh * 64 + qr0) * 64;
  const bf16* Kp = kb_ + (size_t)bh * 4160 * 64;
  const bf16* Vt = vb_ + (size_t)bh * 64 * 4160;

  bf16x8_t qf[2];
#pragma unroll
  for (int kk = 0; kk < 2; ++kk)
    qf[kk] = *(const bf16x8_t*)(q + lr * 64 + kk * 32 + lg * 8);

  f32x4_t oacc[4];
  float m[4], lsum[4];
#pragma unroll
  for (int r = 0; r < 4; ++r) { m[r] = -1e30f; lsum[r] = 0.f; }
#pragma unroll
  for (int nf = 0; nf < 4; ++nf) oacc[nf] = f32x4_t{0.f, 0.f, 0.f, 0.f};

  __shared__ bf16 plds[4][16][72];
  bf16(*P)[72] = plds[wave];

  constexpr float inv = 1.0f / 64.0f;

  bf16x8_t kf[2][4];
  auto ldK = [&](int key0) {
#pragma unroll
    for (int kk = 0; kk < 2; ++kk)
#pragma unroll
      for (int nf = 0; nf < 4; ++nf)
        kf[kk][nf] = *(const bf16x8_t*)(Kp + (size_t)(key0 + nf * 16 + lr) * 64 + kk * 32 + lg * 8);
  };

  ldK(c * 832);
  for (int kt = 0; kt < 13; ++kt) {
    const int key0 = c * 832 + kt * 64;
    f32x4_t sf[4];
#pragma unroll
    for (int nf = 0; nf < 4; ++nf) sf[nf] = f32x4_t{0.f, 0.f, 0.f, 0.f};
#pragma unroll
    for (int kk = 0; kk < 2; ++kk)
#pragma unroll
      for (int nf = 0; nf < 4; ++nf)
        sf[nf] = mfma16(qf[kk], kf[kk][nf], sf[nf]);
    if (kt + 1 < 13) ldK(key0 + 64);
    float corr[4];
#pragma unroll
    for (int r = 0; r < 4; ++r) {
      float t = fmaxf(fmaxf(sf[0][r], sf[1][r]), fmaxf(sf[2][r], sf[3][r])) * inv;
#pragma unroll
      for (int off = 1; off < 16; off <<= 1) t = fmaxf(t, __shfl_xor(t, off));
      const float mn = fmaxf(t, m[r]);
      corr[r] = __expf(m[r] - mn);
      m[r] = mn;
    }
    float rowsum[4] = {0.f, 0.f, 0.f, 0.f};
#pragma unroll
    for (int nf = 0; nf < 4; ++nf)
#pragma unroll
      for (int r = 0; r < 4; ++r) {
        const float p = __expf(sf[nf][r] * inv - m[r]);
        rowsum[r] += p;
        P[lg * 4 + r][nf * 16 + lr] = (bf16)p;
      }
#pragma unroll
    for (int r = 0; r < 4; ++r) {
      float t = rowsum[r];
#pragma unroll
      for (int off = 1; off < 16; off <<= 1) t += __shfl_xor(t, off);
      lsum[r] = lsum[r] * corr[r] + t;
    }
#pragma unroll
    for (int nf = 0; nf < 4; ++nf) {
      oacc[nf][0] *= corr[0];
      oacc[nf][1] *= corr[1];
      oacc[nf][2] *= corr[2];
      oacc[nf][3] *= corr[3];
    }
    bf16x8_t vf[2][4];
#pragma unroll
    for (int kk = 0; kk < 2; ++kk)
#pragma unroll
      for (int nf = 0; nf < 4; ++nf)
        vf[kk][nf] = *(const bf16x8_t*)(Vt + (size_t)(nf * 16 + lr) * 4160 + key0 + kk * 32 + lg * 8);
    asm volatile("s_waitcnt lgkmcnt(0)" ::: "memory");
#pragma unroll
    for (int kk = 0; kk < 2; ++kk) {
      bf16x8_t pf = *(const bf16x8_t*)&P[lr][kk * 32 + lg * 8];
#pragma unroll
      for (int nf = 0; nf < 4; ++nf)
        oacc[nf] = mfma16(pf, vf[kk][nf], oacc[nf]);
    }
    asm volatile("s_waitcnt lgkmcnt(0)" ::: "memory");
  }

#pragma unroll
  for (int nf = 0; nf < 4; ++nf)
#pragma unroll
    for (int r = 0; r < 4; ++r) {
      const int i = qr0 + lg * 4 + r;
      ob[((size_t)((bh * 64 + i) * 5 + c)) * 64 + nf * 16 + lr] = oacc[nf][r];
    }
  if (lr == 0) {
#pragma unroll
    for (int r = 0; r < 4; ++r) {
      const int i = qr0 + lg * 4 + r;
      mb[(bh * 64 + i) * 5 + c] = m[r];
      lb[(bh * 64 + i) * 5 + c] = lsum[r];
    }
  }
}

// ---------------- merge partials -> aout[b*64+i][h*64+d] bf16 ----------------
__global__ __launch_bounds__(256) void attn_merge(const float* __restrict__ ob,
                                                  const float* __restrict__ mb,
                                                  const float* __restrict__ lb,
                                                  bf16* __restrict__ aout) {
  const int j = blockIdx.x * 4 + (threadIdx.x >> 6);  // row 0..8191
  const int l = threadIdx.x & 63;
  float mv[5];
  float mx = -1e30f;
#pragma unroll
  for (int cc = 0; cc < 5; ++cc) { mv[cc] = mb[j * 5 + cc]; mx = fmaxf(mx, mv[cc]); }
  float L = 0.f, o = 0.f;
#pragma unroll
  for (int cc = 0; cc < 5; ++cc) {
    const float wgt = __expf(mv[cc] - mx);
    L += lb[j * 5 + cc] * wgt;
    o += wgt * ob[((size_t)(j * 5 + cc)) * 64 + l];
  }
  const int bh = j >> 6, i = j & 63, b = bh >> 4, h = bh & 15;
  aout[((size_t)(b * 64 + i)) * 1024 + h * 64 + l] = (bf16)(o / L);
}

// ---------------- launch ----------------
extern "C" void kernel_launch(void* const* d_in, const int* in_sizes, int n_in,
                              void* d_out, int out_size, void* d_ws, size_t ws_size,
                              hipStream_t stream) {
  (void)in_sizes; (void)n_in; (void)out_size; (void)ws_size;
  const float* x   = (const float*)d_in[0];
  const float* lat = (const float*)d_in[1];
  const float* g1  = (const float*)d_in[2];
  const float* b1  = (const float*)d_in[3];
  const float* g2  = (const float*)d_in[4];
  const float* b2  = (const float*)d_in[5];
  const float* Wq  = (const float*)d_in[6];
  const float* Wkv = (const float*)d_in[7];
  const float* Wo  = (const float*)d_in[8];
  float* out = (float*)d_out;

  char* ws = (char*)d_ws;
  size_t off = 0;
  auto alloc = [&](size_t bytes) {
    void* p = ws + off;
    off += (bytes + 255) & ~(size_t)255;
    return p;
  };
  bf16* kv_in = (bf16*)alloc(8ull * 4160 * 1024 * 2);     // concat(xn, ln) rows
  bf16* Wkv_t = (bf16*)alloc(2048ull * 1024 * 2);
  bf16* Wq_t  = (bf16*)alloc(1024ull * 1024 * 2);
  bf16* Wo_t  = (bf16*)alloc(1024ull * 1024 * 2);
  bf16* lnq   = (bf16*)alloc(512ull * 1024 * 2);
  bf16* qbuf  = (bf16*)alloc(512ull * 1024 * 2);          // [b,h,i,d]
  bf16* kbuf  = (bf16*)alloc(8ull * 16 * 4160 * 64 * 2);  // [b,h,s,d]
  bf16* vtbuf = (bf16*)alloc(8ull * 16 * 4160 * 64 * 2);  // [b,h,d,s]
  bf16* aout  = (bf16*)alloc(512ull * 1024 * 2);          // [b*64+i, h*64+d]

  // attention partials aliased into kv_in (dead after gemm256_kv)
  float* obuf = (float*)kv_in;           // 8192 * 5 * 64 f32
  float* mbuf = obuf + 8192ull * 5 * 64; // 8192 * 5
  float* lbuf = mbuf + 8192ull * 5;

  (void)hipFuncSetAttribute(reinterpret_cast<const void*>(gemm256_kv),
                            hipFuncAttributeMaxDynamicSharedMemorySize, 65536);

  prep_all<<<12416, 256, 0, stream>>>(x, lat, g1, b1, g2, b2, Wq, Wkv, Wo,
                                      kv_in, lnq, Wq_t, Wkv_t, Wo_t);

  gemm256_kv<<<1048, 512, 65536, stream>>>(kv_in, lnq, Wkv_t, Wq_t, kbuf, vtbuf, qbuf);

  attn_part<<<dim3(5, 128), 256, 0, stream>>>(qbuf, kbuf, vtbuf, obuf, mbuf, lbuf);
  attn_merge<<<2048, 256, 0, stream>>>(obuf, mbuf, lbuf, aout);

  (void)hipMemsetAsync(out, 0, 512ull * 1024 * 4, stream);
  gemm_bt_sk<<<dim3(8, 4, 4), 256, 0, stream>>>(aout, Wo_t, out);
}

// Round 9
// 437.267 us; speedup vs baseline: 3.8078x; 3.8078x over previous
//
#include <hip/hip_runtime.h>

typedef __bf16 bf16;
typedef bf16 bf16x4_t __attribute__((ext_vector_type(4)));
typedef bf16 bf16x8_t __attribute__((ext_vector_type(8)));
typedef float f32x4_t __attribute__((ext_vector_type(4)));

#define DI __device__ __forceinline__

DI void gload_lds16(const void* g, void* l) {
  __builtin_amdgcn_global_load_lds((const __attribute__((address_space(1))) void*)g,
                                   (__attribute__((address_space(3))) void*)l, 16, 0, 0);
}

DI f32x4_t mfma16(bf16x8_t a, bf16x8_t b, f32x4_t c) {
  return __builtin_amdgcn_mfma_f32_16x16x32_bf16(a, b, c, 0, 0, 0);
}

DI unsigned short bfbits(float f) {
  bf16 h = (bf16)f;
  return __builtin_bit_cast(unsigned short, h);
}

// ---------------- fused prep: LN (1 wave/row) + weight transposes ----------------
__global__ __launch_bounds__(256) void prep_all(const float* __restrict__ x,
                                                const float* __restrict__ lat,
                                                const float* __restrict__ g1,
                                                const float* __restrict__ b1,
                                                const float* __restrict__ g2,
                                                const float* __restrict__ b2,
                                                const float* __restrict__ Wq,
                                                const float* __restrict__ Wkv,
                                                const float* __restrict__ Wo,
                                                bf16* __restrict__ kv_in,
                                                bf16* __restrict__ lnq,
                                                bf16* __restrict__ Wq_t,
                                                bf16* __restrict__ Wkv_t,
                                                bf16* __restrict__ Wo_t) {
  const int bid = blockIdx.x;
  const int t = threadIdx.x;
  if (bid < 8320) {
    const int wv = t >> 6, l = t & 63;
    const int row = bid * 4 + wv;
    const float* in;
    const float* gamma;
    const float* beta;
    size_t orow;
    bool dual = false;
    int lrow = 0;
    if (row < 32768) {
      in = x + (size_t)row * 1024;
      gamma = g1; beta = b1;
      orow = (size_t)(row >> 12) * 4160 + (row & 4095);
    } else {
      const int r = row - 32768;
      in = lat + (size_t)r * 1024;
      gamma = g2; beta = b2;
      orow = (size_t)(r >> 6) * 4160 + 4096 + (r & 63);
      dual = true;
      lrow = r;
    }
    float4 v[4];
    float s = 0.f, q = 0.f;
#pragma unroll
    for (int i = 0; i < 4; ++i) {
      v[i] = ((const float4*)in)[i * 64 + l];
      s += v[i].x + v[i].y + v[i].z + v[i].w;
      q += v[i].x * v[i].x + v[i].y * v[i].y + v[i].z * v[i].z + v[i].w * v[i].w;
    }
#pragma unroll
    for (int off = 1; off < 64; off <<= 1) {
      s += __shfl_xor(s, off);
      q += __shfl_xor(q, off);
    }
    const float mu = s * (1.f / 1024.f);
    const float var = q * (1.f / 1024.f) - mu * mu;
    const float rs = rsqrtf(var + 1e-5f);
#pragma unroll
    for (int i = 0; i < 4; ++i) {
      const float4 gv = ((const float4*)gamma)[i * 64 + l];
      const float4 bv = ((const float4*)beta)[i * 64 + l];
      bf16x4_t o;
      o[0] = (bf16)((v[i].x - mu) * rs * gv.x + bv.x);
      o[1] = (bf16)((v[i].y - mu) * rs * gv.y + bv.y);
      o[2] = (bf16)((v[i].z - mu) * rs * gv.z + bv.z);
      o[3] = (bf16)((v[i].w - mu) * rs * gv.w + bv.w);
      *(bf16x4_t*)(kv_in + orow * 1024 + i * 256 + l * 4) = o;
      if (dual) *(bf16x4_t*)(lnq + (size_t)lrow * 1024 + i * 256 + l * 4) = o;
    }
  } else {
    __shared__ float tile[32][33];
    const int b2i = bid - 8320;
    const float* W;
    bf16* Wt;
    int C, t0;
    if (b2i < 1024)      { W = Wq;  Wt = Wq_t;  C = 1024; t0 = b2i; }
    else if (b2i < 3072) { W = Wkv; Wt = Wkv_t; C = 2048; t0 = b2i - 1024; }
    else                 { W = Wo;  Wt = Wo_t;  C = 1024; t0 = b2i - 3072; }
    const int R = 1024;
    const int ntx = C >> 5;
    const int c0 = (t0 % ntx) * 32, r0 = (t0 / ntx) * 32;
    const int tx = t & 31, ty = t >> 5;
#pragma unroll
    for (int j = 0; j < 4; ++j)
      tile[ty + j * 8][tx] = W[(size_t)(r0 + ty + j * 8) * C + c0 + tx];
    __syncthreads();
#pragma unroll
    for (int j = 0; j < 4; ++j)
      Wt[(size_t)(c0 + ty + j * 8) * R + r0 + tx] = (bf16)tile[tx][ty + j * 8];
  }
}

// ---------------- out GEMM, split-K=4, atomic f32 accumulate ----------------
__global__ __launch_bounds__(256) void gemm_bt_sk(const bf16* __restrict__ A,
                                                  const bf16* __restrict__ Bt,
                                                  float* __restrict__ Cf) {
  __shared__ bf16 As[128 * 32];
  __shared__ bf16 Bs[128 * 32];
  const int tid = threadIdx.x;
  const int w = tid >> 6, l = tid & 63;
  const int lg = l >> 4, lr = l & 15;
  const int m0 = blockIdx.y * 128, n0 = blockIdx.x * 128;
  const int kbase = blockIdx.z * 256;
  const int wm = w >> 1, wn = w & 1;
  const int K = 1024, N = 1024;

  f32x4_t acc[4][4];
#pragma unroll
  for (int i = 0; i < 4; ++i)
#pragma unroll
    for (int j = 0; j < 4; ++j)
      acc[i][j] = f32x4_t{0.f, 0.f, 0.f, 0.f};

  for (int kt = 0; kt < 8; ++kt) {
    const int k0 = kbase + kt * 32;
#pragma unroll
    for (int j = 0; j < 2; ++j) {
      const int rb = j * 64 + w * 16;
      const int r = rb + (l >> 2);
      const int c = (l & 3) * 8;
      gload_lds16(A + (size_t)(m0 + r) * K + k0 + c, &As[rb * 32]);
      gload_lds16(Bt + (size_t)(n0 + r) * K + k0 + c, &Bs[rb * 32]);
    }
    __syncthreads();
    bf16x8_t af[4], bfr[4];
#pragma unroll
    for (int i = 0; i < 4; ++i) {
      af[i] = *(const bf16x8_t*)&As[(wm * 64 + i * 16 + lr) * 32 + lg * 8];
      bfr[i] = *(const bf16x8_t*)&Bs[(wn * 64 + i * 16 + lr) * 32 + lg * 8];
    }
#pragma unroll
    for (int mf = 0; mf < 4; ++mf)
#pragma unroll
      for (int nf = 0; nf < 4; ++nf)
        acc[mf][nf] = mfma16(af[mf], bfr[nf], acc[mf][nf]);
    __syncthreads();
  }

#pragma unroll
  for (int mf = 0; mf < 4; ++mf)
#pragma unroll
    for (int r = 0; r < 4; ++r) {
      const int grow = m0 + wm * 64 + mf * 16 + 4 * lg + r;
#pragma unroll
      for (int nf = 0; nf < 4; ++nf) {
        const int gcol = n0 + wn * 64 + nf * 16 + lr;
        unsafeAtomicAdd(&Cf[(size_t)grow * N + gcol], acc[mf][nf][r]);
      }
    }
}

// ---------------- 256x256 GEMM, single-buffered 64KB LDS, 2 blocks/CU ----------------
// NOTE: __launch_bounds__ 2nd arg with 512-thread blocks empirically acts as
// blocks/CU on this toolchain: (512,4) forced 64 VGPR + massive spill (R8);
// (512,2) gives exactly the 128-VGPR / 16-wave configuration we want.
__global__ __launch_bounds__(512, 2) void gemm256_kv(const bf16* __restrict__ Akv,
                                                     const bf16* __restrict__ Aq,
                                                     const bf16* __restrict__ BtKV,
                                                     const bf16* __restrict__ BtQ,
                                                     bf16* __restrict__ Kout,
                                                     bf16* __restrict__ Vout,
                                                     bf16* __restrict__ Qout) {
  extern __shared__ char lds[];
  const int tid = threadIdx.x;
  const int w = tid >> 6, l = tid & 63;
  const int lr = l & 15, lg = l >> 4;
  const int wr = w >> 2, wc = w & 3;

  const int cpx = gridDim.x >> 3;
  const int swz = (blockIdx.x & 7) * cpx + (blockIdx.x >> 3);
  const bool isQ = swz >= 1040;
  const bf16* Ap;
  const bf16* Bp;
  int m0, n0;
  if (!isQ) {
    m0 = (swz >> 3) << 8;
    n0 = (swz & 7) << 8;
    Ap = Akv; Bp = BtKV;
  } else {
    const int qi = swz - 1040;
    m0 = (qi >> 2) << 8;
    n0 = (qi & 3) << 8;
    Ap = Aq; Bp = BtQ;
  }

  auto stage = [&](const bf16* __restrict__ G, int row0, int k0, char* base, int half) {
#pragma unroll
    for (int j = 0; j < 2; ++j) {
      const int r0 = half * 128 + (w * 2 + j) * 8;
      const int row = r0 + (l >> 3);
      const int col = ((l & 7) ^ (l >> 3)) * 8;
      gload_lds16(G + (size_t)(row0 + row) * 1024 + k0 + col, base + r0 * 128);
    }
  };
  auto rdA = [&](char* base, int mf, int ks) -> bf16x8_t {
    const int row = wr * 128 + mf * 16 + lr;
    int byte = row * 128 + (ks * 32 + lg * 8) * 2;
    byte ^= (row & 7) << 4;
    return *(const bf16x8_t*)(base + byte);
  };
  auto rdB = [&](char* base, int nf, int ks) -> bf16x8_t {
    const int row = wc * 64 + nf * 16 + lr;
    int byte = row * 128 + (ks * 32 + lg * 8) * 2;
    byte ^= (row & 7) << 4;
    return *(const bf16x8_t*)(base + byte);
  };

  f32x4_t acc[8][4];
#pragma unroll
  for (int i = 0; i < 8; ++i)
#pragma unroll
    for (int j = 0; j < 4; ++j)
      acc[i][j] = f32x4_t{0.f, 0.f, 0.f, 0.f};

  char* Ab = lds;          // 32KB: 256 rows x 128B
  char* Bb = lds + 32768;  // 32KB

  const int NK = 16;

  stage(Ap, m0, 0, Ab, 0);
  stage(Ap, m0, 0, Ab, 1);
  stage(Bp, n0, 0, Bb, 0);
  stage(Bp, n0, 0, Bb, 1);
  asm volatile("s_waitcnt vmcnt(0)" ::: "memory");
  __builtin_amdgcn_s_barrier();

  bf16x8_t ra[4][2], rb[4][2];
  for (int kt = 0; kt < NK; ++kt) {
    const int k1 = (kt + 1) << 6;

    // ---- phase 0: read A mf0-3, B nf0-1; bar; MFMA
#pragma unroll
    for (int mf = 0; mf < 4; ++mf) { ra[mf][0] = rdA(Ab, mf, 0); ra[mf][1] = rdA(Ab, mf, 1); }
#pragma unroll
    for (int nf = 0; nf < 2; ++nf) { rb[nf][0] = rdB(Bb, nf, 0); rb[nf][1] = rdB(Bb, nf, 1); }
    asm volatile("s_waitcnt lgkmcnt(0)" ::: "memory");
    __builtin_amdgcn_sched_barrier(0);
    __builtin_amdgcn_s_barrier();
    __builtin_amdgcn_s_setprio(1);
#pragma unroll
    for (int mf = 0; mf < 4; ++mf)
#pragma unroll
      for (int nf = 0; nf < 2; ++nf) {
        acc[mf][nf] = mfma16(ra[mf][0], rb[nf][0], acc[mf][nf]);
        acc[mf][nf] = mfma16(ra[mf][1], rb[nf][1], acc[mf][nf]);
      }
    __builtin_amdgcn_s_setprio(0);

    // ---- phase 1: read B nf2-3; bar; MFMA  (after this bar ALL B reads are drained)
#pragma unroll
    for (int nf = 2; nf < 4; ++nf) { rb[nf][0] = rdB(Bb, nf, 0); rb[nf][1] = rdB(Bb, nf, 1); }
    asm volatile("s_waitcnt lgkmcnt(0)" ::: "memory");
    __builtin_amdgcn_sched_barrier(0);
    __builtin_amdgcn_s_barrier();
    __builtin_amdgcn_s_setprio(1);
#pragma unroll
    for (int mf = 0; mf < 4; ++mf)
#pragma unroll
      for (int nf = 2; nf < 4; ++nf) {
        acc[mf][nf] = mfma16(ra[mf][0], rb[nf][0], acc[mf][nf]);
        acc[mf][nf] = mfma16(ra[mf][1], rb[nf][1], acc[mf][nf]);
      }
    __builtin_amdgcn_s_setprio(0);

    // ---- phase 2: read A mf4-7; restage B(kt+1) in place; bar; MFMA
#pragma unroll
    for (int mf = 0; mf < 4; ++mf) { ra[mf][0] = rdA(Ab, mf + 4, 0); ra[mf][1] = rdA(Ab, mf + 4, 1); }
    if (kt + 1 < NK) { stage(Bp, n0, k1, Bb, 0); stage(Bp, n0, k1, Bb, 1); }
    asm volatile("s_waitcnt lgkmcnt(0)" ::: "memory");
    __builtin_amdgcn_sched_barrier(0);
    __builtin_amdgcn_s_barrier();
    __builtin_amdgcn_s_setprio(1);
#pragma unroll
    for (int mf = 0; mf < 4; ++mf)
#pragma unroll
      for (int nf = 0; nf < 2; ++nf) {
        acc[mf + 4][nf] = mfma16(ra[mf][0], rb[nf][0], acc[mf + 4][nf]);
        acc[mf + 4][nf] = mfma16(ra[mf][1], rb[nf][1], acc[mf + 4][nf]);
      }
    __builtin_amdgcn_s_setprio(0);

    // ---- phase 3: restage A(kt+1) in place; vmcnt(0); bar; MFMA
    if (kt + 1 < NK) { stage(Ap, m0, k1, Ab, 0); stage(Ap, m0, k1, Ab, 1); }
    asm volatile("s_waitcnt vmcnt(0)" ::: "memory");
    __builtin_amdgcn_sched_barrier(0);
    __builtin_amdgcn_s_barrier();
    __builtin_amdgcn_s_setprio(1);
#pragma unroll
    for (int mf = 0; mf < 4; ++mf)
#pragma unroll
      for (int nf = 2; nf < 4; ++nf) {
        acc[mf + 4][nf] = mfma16(ra[mf][0], rb[nf][0], acc[mf + 4][nf]);
        acc[mf + 4][nf] = mfma16(ra[mf][1], rb[nf][1], acc[mf + 4][nf]);
      }
    __builtin_amdgcn_s_setprio(0);
  }

  if (isQ) {
#pragma unroll
    for (int mf = 0; mf < 8; ++mf) {
      const int grow0 = m0 + wr * 128 + mf * 16 + 4 * lg;
#pragma unroll
      for (int nf = 0; nf < 4; ++nf) {
        const int gcol = n0 + wc * 64 + nf * 16 + lr;
        const int h = gcol >> 6, d = gcol & 63;
#pragma unroll
        for (int r = 0; r < 4; ++r) {
          const int grow = grow0 + r;
          const int b = grow >> 6, i = grow & 63;
          Qout[((size_t)((b * 16 + h) * 64 + i)) * 64 + d] = (bf16)acc[mf][nf][r];
        }
      }
    }
    return;
  }
#pragma unroll
  for (int mf = 0; mf < 8; ++mf) {
    const int grow0 = m0 + wr * 128 + mf * 16 + 4 * lg;
#pragma unroll
    for (int nf = 0; nf < 4; ++nf) {
      const int gcol = n0 + wc * 64 + nf * 16 + lr;
      if (gcol < 1024) {
        const int h = gcol >> 6, d = gcol & 63;
#pragma unroll
        for (int r = 0; r < 4; ++r) {
          const int grow = grow0 + r;
          const int bb = grow / 4160, s = grow % 4160;
          Kout[((size_t)((bb * 16 + h) * 4160 + s)) * 64 + d] = (bf16)acc[mf][nf][r];
        }
      } else {
        const int c2 = gcol - 1024, h = c2 >> 6, d = c2 & 63;
        const int bb = grow0 / 4160, s0 = grow0 % 4160;
        ushort4 u;
        u.x = bfbits(acc[mf][nf][0]);
        u.y = bfbits(acc[mf][nf][1]);
        u.z = bfbits(acc[mf][nf][2]);
        u.w = bfbits(acc[mf][nf][3]);
        *(ushort4*)&Vout[((size_t)((bb * 16 + h) * 64 + d)) * 4160 + s0] = u;
      }
    }
  }
}

// ---------------- flash attention partials: 4 independent waves/WG, 5 kv-chunks ----------------
__global__ __launch_bounds__(256) void attn_part(const bf16* __restrict__ qb_,
                                                 const bf16* __restrict__ kb_,
                                                 const bf16* __restrict__ vb_,
                                                 float* __restrict__ ob,
                                                 float* __restrict__ mb,
                                                 float* __restrict__ lb) {
  const int c = blockIdx.x;   // 0..4
  const int bh = blockIdx.y;  // 0..127
  const int tid = threadIdx.x;
  const int wave = tid >> 6, l = tid & 63;
  const int lg = l >> 4, lr = l & 15;
  const int qr0 = wave * 16;

  const bf16* q = qb_ + ((size_t)bh * 64 + qr0) * 64;
  const bf16* Kp = kb_ + (size_t)bh * 4160 * 64;
  const bf16* Vt = vb_ + (size_t)bh * 64 * 4160;

  bf16x8_t qf[2];
#pragma unroll
  for (int kk = 0; kk < 2; ++kk)
    qf[kk] = *(const bf16x8_t*)(q + lr * 64 + kk * 32 + lg * 8);

  f32x4_t oacc[4];
  float m[4], lsum[4];
#pragma unroll
  for (int r = 0; r < 4; ++r) { m[r] = -1e30f; lsum[r] = 0.f; }
#pragma unroll
  for (int nf = 0; nf < 4; ++nf) oacc[nf] = f32x4_t{0.f, 0.f, 0.f, 0.f};

  __shared__ bf16 plds[4][16][72];
  bf16(*P)[72] = plds[wave];

  constexpr float inv = 1.0f / 64.0f;

  bf16x8_t kf[2][4];
  auto ldK = [&](int key0) {
#pragma unroll
    for (int kk = 0; kk < 2; ++kk)
#pragma unroll
      for (int nf = 0; nf < 4; ++nf)
        kf[kk][nf] = *(const bf16x8_t*)(Kp + (size_t)(key0 + nf * 16 + lr) * 64 + kk * 32 + lg * 8);
  };

  ldK(c * 832);
  for (int kt = 0; kt < 13; ++kt) {
    const int key0 = c * 832 + kt * 64;
    f32x4_t sf[4];
#pragma unroll
    for (int nf = 0; nf < 4; ++nf) sf[nf] = f32x4_t{0.f, 0.f, 0.f, 0.f};
#pragma unroll
    for (int kk = 0; kk < 2; ++kk)
#pragma unroll
      for (int nf = 0; nf < 4; ++nf)
        sf[nf] = mfma16(qf[kk], kf[kk][nf], sf[nf]);
    if (kt + 1 < 13) ldK(key0 + 64);
    float corr[4];
#pragma unroll
    for (int r = 0; r < 4; ++r) {
      float t = fmaxf(fmaxf(sf[0][r], sf[1][r]), fmaxf(sf[2][r], sf[3][r])) * inv;
#pragma unroll
      for (int off = 1; off < 16; off <<= 1) t = fmaxf(t, __shfl_xor(t, off));
      const float mn = fmaxf(t, m[r]);
      corr[r] = __expf(m[r] - mn);
      m[r] = mn;
    }
    float rowsum[4] = {0.f, 0.f, 0.f, 0.f};
#pragma unroll
    for (int nf = 0; nf < 4; ++nf)
#pragma unroll
      for (int r = 0; r < 4; ++r) {
        const float p = __expf(sf[nf][r] * inv - m[r]);
        rowsum[r] += p;
        P[lg * 4 + r][nf * 16 + lr] = (bf16)p;
      }
#pragma unroll
    for (int r = 0; r < 4; ++r) {
      float t = rowsum[r];
#pragma unroll
      for (int off = 1; off < 16; off <<= 1) t += __shfl_xor(t, off);
      lsum[r] = lsum[r] * corr[r] + t;
    }
#pragma unroll
    for (int nf = 0; nf < 4; ++nf) {
      oacc[nf][0] *= corr[0];
      oacc[nf][1] *= corr[1];
      oacc[nf][2] *= corr[2];
      oacc[nf][3] *= corr[3];
    }
    bf16x8_t vf[2][4];
#pragma unroll
    for (int kk = 0; kk < 2; ++kk)
#pragma unroll
      for (int nf = 0; nf < 4; ++nf)
        vf[kk][nf] = *(const bf16x8_t*)(Vt + (size_t)(nf * 16 + lr) * 4160 + key0 + kk * 32 + lg * 8);
    asm volatile("s_waitcnt lgkmcnt(0)" ::: "memory");
#pragma unroll
    for (int kk = 0; kk < 2; ++kk) {
      bf16x8_t pf = *(const bf16x8_t*)&P[lr][kk * 32 + lg * 8];
#pragma unroll
      for (int nf = 0; nf < 4; ++nf)
        oacc[nf] = mfma16(pf, vf[kk][nf], oacc[nf]);
    }
    asm volatile("s_waitcnt lgkmcnt(0)" ::: "memory");
  }

#pragma unroll
  for (int nf = 0; nf < 4; ++nf)
#pragma unroll
    for (int r = 0; r < 4; ++r) {
      const int i = qr0 + lg * 4 + r;
      ob[((size_t)((bh * 64 + i) * 5 + c)) * 64 + nf * 16 + lr] = oacc[nf][r];
    }
  if (lr == 0) {
#pragma unroll
    for (int r = 0; r < 4; ++r) {
      const int i = qr0 + lg * 4 + r;
      mb[(bh * 64 + i) * 5 + c] = m[r];
      lb[(bh * 64 + i) * 5 + c] = lsum[r];
    }
  }
}

// ---------------- merge partials -> aout[b*64+i][h*64+d] bf16 ----------------
__global__ __launch_bounds__(256) void attn_merge(const float* __restrict__ ob,
                                                  const float* __restrict__ mb,
                                                  const float* __restrict__ lb,
                                                  bf16* __restrict__ aout) {
  const int j = blockIdx.x * 4 + (threadIdx.x >> 6);  // row 0..8191
  const int l = threadIdx.x & 63;
  float mv[5];
  float mx = -1e30f;
#pragma unroll
  for (int cc = 0; cc < 5; ++cc) { mv[cc] = mb[j * 5 + cc]; mx = fmaxf(mx, mv[cc]); }
  float L = 0.f, o = 0.f;
#pragma unroll
  for (int cc = 0; cc < 5; ++cc) {
    const float wgt = __expf(mv[cc] - mx);
    L += lb[j * 5 + cc] * wgt;
    o += wgt * ob[((size_t)(j * 5 + cc)) * 64 + l];
  }
  const int bh = j >> 6, i = j & 63, b = bh >> 4, h = bh & 15;
  aout[((size_t)(b * 64 + i)) * 1024 + h * 64 + l] = (bf16)(o / L);
}

// ---------------- launch ----------------
extern "C" void kernel_launch(void* const* d_in, const int* in_sizes, int n_in,
                              void* d_out, int out_size, void* d_ws, size_t ws_size,
                              hipStream_t stream) {
  (void)in_sizes; (void)n_in; (void)out_size; (void)ws_size;
  const float* x   = (const float*)d_in[0];
  const float* lat = (const float*)d_in[1];
  const float* g1  = (const float*)d_in[2];
  const float* b1  = (const float*)d_in[3];
  const float* g2  = (const float*)d_in[4];
  const float* b2  = (const float*)d_in[5];
  const float* Wq  = (const float*)d_in[6];
  const float* Wkv = (const float*)d_in[7];
  const float* Wo  = (const float*)d_in[8];
  float* out = (float*)d_out;

  char* ws = (char*)d_ws;
  size_t off = 0;
  auto alloc = [&](size_t bytes) {
    void* p = ws + off;
    off += (bytes + 255) & ~(size_t)255;
    return p;
  };
  bf16* kv_in = (bf16*)alloc(8ull * 4160 * 1024 * 2);     // concat(xn, ln) rows
  bf16* Wkv_t = (bf16*)alloc(2048ull * 1024 * 2);
  bf16* Wq_t  = (bf16*)alloc(1024ull * 1024 * 2);
  bf16* Wo_t  = (bf16*)alloc(1024ull * 1024 * 2);
  bf16* lnq   = (bf16*)alloc(512ull * 1024 * 2);
  bf16* qbuf  = (bf16*)alloc(512ull * 1024 * 2);          // [b,h,i,d]
  bf16* kbuf  = (bf16*)alloc(8ull * 16 * 4160 * 64 * 2);  // [b,h,s,d]
  bf16* vtbuf = (bf16*)alloc(8ull * 16 * 4160 * 64 * 2);  // [b,h,d,s]
  bf16* aout  = (bf16*)alloc(512ull * 1024 * 2);          // [b*64+i, h*64+d]

  // attention partials aliased into kv_in (dead after gemm256_kv)
  float* obuf = (float*)kv_in;           // 8192 * 5 * 64 f32
  float* mbuf = obuf + 8192ull * 5 * 64; // 8192 * 5
  float* lbuf = mbuf + 8192ull * 5;

  (void)hipFuncSetAttribute(reinterpret_cast<const void*>(gemm256_kv),
                            hipFuncAttributeMaxDynamicSharedMemorySize, 65536);

  prep_all<<<12416, 256, 0, stream>>>(x, lat, g1, b1, g2, b2, Wq, Wkv, Wo,
                                      kv_in, lnq, Wq_t, Wkv_t, Wo_t);

  gemm256_kv<<<1048, 512, 65536, stream>>>(kv_in, lnq, Wkv_t, Wq_t, kbuf, vtbuf, qbuf);

  attn_part<<<dim3(5, 128), 256, 0, stream>>>(qbuf, kbuf, vtbuf, obuf, mbuf, lbuf);
  attn_merge<<<2048, 256, 0, stream>>>(obuf, mbuf, lbuf, aout);

  (void)hipMemsetAsync(out, 0, 512ull * 1024 * 4, stream);
  gemm_bt_sk<<<dim3(8, 4, 4), 256, 0, stream>>>(aout, Wo_t, out);
}

// Round 10
// 284.487 us; speedup vs baseline: 5.8528x; 1.5370x over previous
//
#include <hip/hip_runtime.h>

typedef __bf16 bf16;
typedef bf16 bf16x4_t __attribute__((ext_vector_type(4)));
typedef bf16 bf16x8_t __attribute__((ext_vector_type(8)));
typedef float f32x4_t __attribute__((ext_vector_type(4)));

#define DI __device__ __forceinline__

DI void gload_lds16(const void* g, void* l) {
  __builtin_amdgcn_global_load_lds((const __attribute__((address_space(1))) void*)g,
                                   (__attribute__((address_space(3))) void*)l, 16, 0, 0);
}

DI f32x4_t mfma16(bf16x8_t a, bf16x8_t b, f32x4_t c) {
  return __builtin_amdgcn_mfma_f32_16x16x32_bf16(a, b, c, 0, 0, 0);
}

DI unsigned short bfbits(float f) {
  bf16 h = (bf16)f;
  return __builtin_bit_cast(unsigned short, h);
}

// ---------------- fused prep: LN (1 wave/row) + weight transposes ----------------
__global__ __launch_bounds__(256) void prep_all(const float* __restrict__ x,
                                                const float* __restrict__ lat,
                                                const float* __restrict__ g1,
                                                const float* __restrict__ b1,
                                                const float* __restrict__ g2,
                                                const float* __restrict__ b2,
                                                const float* __restrict__ Wq,
                                                const float* __restrict__ Wkv,
                                                const float* __restrict__ Wo,
                                                bf16* __restrict__ kv_in,
                                                bf16* __restrict__ lnq,
                                                bf16* __restrict__ Wq_t,
                                                bf16* __restrict__ Wkv_t,
                                                bf16* __restrict__ Wo_t) {
  const int bid = blockIdx.x;
  const int t = threadIdx.x;
  if (bid < 8320) {
    const int wv = t >> 6, l = t & 63;
    const int row = bid * 4 + wv;
    const float* in;
    const float* gamma;
    const float* beta;
    size_t orow;
    bool dual = false;
    int lrow = 0;
    if (row < 32768) {
      in = x + (size_t)row * 1024;
      gamma = g1; beta = b1;
      orow = (size_t)(row >> 12) * 4160 + (row & 4095);
    } else {
      const int r = row - 32768;
      in = lat + (size_t)r * 1024;
      gamma = g2; beta = b2;
      orow = (size_t)(r >> 6) * 4160 + 4096 + (r & 63);
      dual = true;
      lrow = r;
    }
    float4 v[4];
    float s = 0.f, q = 0.f;
#pragma unroll
    for (int i = 0; i < 4; ++i) {
      v[i] = ((const float4*)in)[i * 64 + l];
      s += v[i].x + v[i].y + v[i].z + v[i].w;
      q += v[i].x * v[i].x + v[i].y * v[i].y + v[i].z * v[i].z + v[i].w * v[i].w;
    }
#pragma unroll
    for (int off = 1; off < 64; off <<= 1) {
      s += __shfl_xor(s, off);
      q += __shfl_xor(q, off);
    }
    const float mu = s * (1.f / 1024.f);
    const float var = q * (1.f / 1024.f) - mu * mu;
    const float rs = rsqrtf(var + 1e-5f);
#pragma unroll
    for (int i = 0; i < 4; ++i) {
      const float4 gv = ((const float4*)gamma)[i * 64 + l];
      const float4 bv = ((const float4*)beta)[i * 64 + l];
      bf16x4_t o;
      o[0] = (bf16)((v[i].x - mu) * rs * gv.x + bv.x);
      o[1] = (bf16)((v[i].y - mu) * rs * gv.y + bv.y);
      o[2] = (bf16)((v[i].z - mu) * rs * gv.z + bv.z);
      o[3] = (bf16)((v[i].w - mu) * rs * gv.w + bv.w);
      *(bf16x4_t*)(kv_in + orow * 1024 + i * 256 + l * 4) = o;
      if (dual) *(bf16x4_t*)(lnq + (size_t)lrow * 1024 + i * 256 + l * 4) = o;
    }
  } else {
    __shared__ float tile[32][33];
    const int b2i = bid - 8320;
    const float* W;
    bf16* Wt;
    int C, t0;
    if (b2i < 1024)      { W = Wq;  Wt = Wq_t;  C = 1024; t0 = b2i; }
    else if (b2i < 3072) { W = Wkv; Wt = Wkv_t; C = 2048; t0 = b2i - 1024; }
    else                 { W = Wo;  Wt = Wo_t;  C = 1024; t0 = b2i - 3072; }
    const int R = 1024;
    const int ntx = C >> 5;
    const int c0 = (t0 % ntx) * 32, r0 = (t0 / ntx) * 32;
    const int tx = t & 31, ty = t >> 5;
#pragma unroll
    for (int j = 0; j < 4; ++j)
      tile[ty + j * 8][tx] = W[(size_t)(r0 + ty + j * 8) * C + c0 + tx];
    __syncthreads();
#pragma unroll
    for (int j = 0; j < 4; ++j)
      Wt[(size_t)(c0 + ty + j * 8) * R + r0 + tx] = (bf16)tile[tx][ty + j * 8];
  }
}

// ---------------- out GEMM, split-K=4, atomic f32 accumulate ----------------
__global__ __launch_bounds__(256) void gemm_bt_sk(const bf16* __restrict__ A,
                                                  const bf16* __restrict__ Bt,
                                                  float* __restrict__ Cf) {
  __shared__ bf16 As[128 * 32];
  __shared__ bf16 Bs[128 * 32];
  const int tid = threadIdx.x;
  const int w = tid >> 6, l = tid & 63;
  const int lg = l >> 4, lr = l & 15;
  const int m0 = blockIdx.y * 128, n0 = blockIdx.x * 128;
  const int kbase = blockIdx.z * 256;
  const int wm = w >> 1, wn = w & 1;
  const int K = 1024, N = 1024;

  f32x4_t acc[4][4];
#pragma unroll
  for (int i = 0; i < 4; ++i)
#pragma unroll
    for (int j = 0; j < 4; ++j)
      acc[i][j] = f32x4_t{0.f, 0.f, 0.f, 0.f};

  for (int kt = 0; kt < 8; ++kt) {
    const int k0 = kbase + kt * 32;
#pragma unroll
    for (int j = 0; j < 2; ++j) {
      const int rb = j * 64 + w * 16;
      const int r = rb + (l >> 2);
      const int c = (l & 3) * 8;
      gload_lds16(A + (size_t)(m0 + r) * K + k0 + c, &As[rb * 32]);
      gload_lds16(Bt + (size_t)(n0 + r) * K + k0 + c, &Bs[rb * 32]);
    }
    __syncthreads();
    bf16x8_t af[4], bfr[4];
#pragma unroll
    for (int i = 0; i < 4; ++i) {
      af[i] = *(const bf16x8_t*)&As[(wm * 64 + i * 16 + lr) * 32 + lg * 8];
      bfr[i] = *(const bf16x8_t*)&Bs[(wn * 64 + i * 16 + lr) * 32 + lg * 8];
    }
#pragma unroll
    for (int mf = 0; mf < 4; ++mf)
#pragma unroll
      for (int nf = 0; nf < 4; ++nf)
        acc[mf][nf] = mfma16(af[mf], bfr[nf], acc[mf][nf]);
    __syncthreads();
  }

#pragma unroll
  for (int mf = 0; mf < 4; ++mf)
#pragma unroll
    for (int r = 0; r < 4; ++r) {
      const int grow = m0 + wm * 64 + mf * 16 + 4 * lg + r;
#pragma unroll
      for (int nf = 0; nf < 4; ++nf) {
        const int gcol = n0 + wn * 64 + nf * 16 + lr;
        unsafeAtomicAdd(&Cf[(size_t)grow * N + gcol], acc[mf][nf][r]);
      }
    }
}

// ---------------- 256x256 4-phase GEMM (R7 config): double-buffered 128KB LDS ----------------
// kv projection (blocks swz<1040) + q projection (8 tail blocks).
// ONE barrier per phase. B staged 1 tile ahead (ph0/ph1 -> nxt buf), A staged 2
// tiles ahead (ph3 -> cur buf, safe after ph2's global lgkmcnt drain).
// vmcnt(4) once/tile leaves A(kt+2) in flight. 1 block/CU (proven best: R9's
// single-buffer 2-block attempt never became co-resident and serial vmcnt(0) cost 2x).
__global__ __launch_bounds__(512, 2) void gemm256_kv(const bf16* __restrict__ Akv,
                                                     const bf16* __restrict__ Aq,
                                                     const bf16* __restrict__ BtKV,
                                                     const bf16* __restrict__ BtQ,
                                                     bf16* __restrict__ Kout,
                                                     bf16* __restrict__ Vout,
                                                     bf16* __restrict__ Qout) {
  extern __shared__ char lds[];
  const int tid = threadIdx.x;
  const int w = tid >> 6, l = tid & 63;
  const int lr = l & 15, lg = l >> 4;
  const int wr = w >> 2, wc = w & 3;

  const int cpx = gridDim.x >> 3;
  const int swz = (blockIdx.x & 7) * cpx + (blockIdx.x >> 3);
  const bool isQ = swz >= 1040;
  const bf16* Ap;
  const bf16* Bp;
  int m0, n0;
  if (!isQ) {
    m0 = (swz >> 3) << 8;
    n0 = (swz & 7) << 8;
    Ap = Akv; Bp = BtKV;
  } else {
    const int qi = swz - 1040;
    m0 = (qi >> 2) << 8;
    n0 = (qi & 3) << 8;
    Ap = Aq; Bp = BtQ;
  }

  auto stage = [&](const bf16* __restrict__ G, int row0, int k0, char* base, int half) {
#pragma unroll
    for (int j = 0; j < 2; ++j) {
      const int r0 = half * 128 + (w * 2 + j) * 8;
      const int row = r0 + (l >> 3);
      const int col = ((l & 7) ^ (l >> 3)) * 8;
      gload_lds16(G + (size_t)(row0 + row) * 1024 + k0 + col, base + r0 * 128);
    }
  };
  auto rdA = [&](char* base, int mf, int ks) -> bf16x8_t {
    const int row = wr * 128 + mf * 16 + lr;
    int byte = row * 128 + (ks * 32 + lg * 8) * 2;
    byte ^= (row & 7) << 4;
    return *(const bf16x8_t*)(base + byte);
  };
  auto rdB = [&](char* base, int nf, int ks) -> bf16x8_t {
    const int row = wc * 64 + nf * 16 + lr;
    int byte = row * 128 + (ks * 32 + lg * 8) * 2;
    byte ^= (row & 7) << 4;
    return *(const bf16x8_t*)(base + byte);
  };

  f32x4_t acc[8][4];
#pragma unroll
  for (int i = 0; i < 8; ++i)
#pragma unroll
    for (int j = 0; j < 4; ++j)
      acc[i][j] = f32x4_t{0.f, 0.f, 0.f, 0.f};

  const int NK = 16;

  // prologue: A(0), B(0), A(1) — oldest-first so vmcnt(4) drains A(0)+B(0)
  stage(Ap, m0, 0, lds, 0);
  stage(Ap, m0, 0, lds, 1);
  stage(Bp, n0, 0, lds + 32768, 0);
  stage(Bp, n0, 0, lds + 32768, 1);
  stage(Ap, m0, 64, lds + 65536, 0);
  stage(Ap, m0, 64, lds + 65536, 1);
  asm volatile("s_waitcnt vmcnt(4)" ::: "memory");
  __builtin_amdgcn_s_barrier();

  bf16x8_t ra[4][2], rb[4][2];
  for (int kt = 0; kt < NK; ++kt) {
    const int cur = kt & 1, nxt = cur ^ 1;
    char* Ac = lds + cur * 65536;
    char* Bc = lds + 32768 + cur * 65536;
    char* Bn = lds + 32768 + nxt * 65536;
    const int k1 = (kt + 1) << 6, k2 = (kt + 2) << 6;

    // ---- phase 0: reads A mf0-3 + B nf0-1; stage B-h0(kt+1); 1 barrier; MFMA
#pragma unroll
    for (int mf = 0; mf < 4; ++mf) { ra[mf][0] = rdA(Ac, mf, 0); ra[mf][1] = rdA(Ac, mf, 1); }
#pragma unroll
    for (int nf = 0; nf < 2; ++nf) { rb[nf][0] = rdB(Bc, nf, 0); rb[nf][1] = rdB(Bc, nf, 1); }
    if (kt + 1 < NK) stage(Bp, n0, k1, Bn, 0);
    asm volatile("s_waitcnt lgkmcnt(0)" ::: "memory");
    __builtin_amdgcn_sched_barrier(0);
    __builtin_amdgcn_s_barrier();
    __builtin_amdgcn_s_setprio(1);
#pragma unroll
    for (int mf = 0; mf < 4; ++mf)
#pragma unroll
      for (int nf = 0; nf < 2; ++nf) {
        acc[mf][nf] = mfma16(ra[mf][0], rb[nf][0], acc[mf][nf]);
        acc[mf][nf] = mfma16(ra[mf][1], rb[nf][1], acc[mf][nf]);
      }
    __builtin_amdgcn_s_setprio(0);

    // ---- phase 1: reads B nf2-3; stage B-h1(kt+1); 1 barrier; MFMA
#pragma unroll
    for (int nf = 2; nf < 4; ++nf) { rb[nf][0] = rdB(Bc, nf, 0); rb[nf][1] = rdB(Bc, nf, 1); }
    if (kt + 1 < NK) stage(Bp, n0, k1, Bn, 1);
    asm volatile("s_waitcnt lgkmcnt(0)" ::: "memory");
    __builtin_amdgcn_sched_barrier(0);
    __builtin_amdgcn_s_barrier();
    __builtin_amdgcn_s_setprio(1);
#pragma unroll
    for (int mf = 0; mf < 4; ++mf)
#pragma unroll
      for (int nf = 2; nf < 4; ++nf) {
        acc[mf][nf] = mfma16(ra[mf][0], rb[nf][0], acc[mf][nf]);
        acc[mf][nf] = mfma16(ra[mf][1], rb[nf][1], acc[mf][nf]);
      }
    __builtin_amdgcn_s_setprio(0);

    // ---- phase 2: reads A mf4-7; 1 barrier; MFMA (all A-cur reads drained here)
#pragma unroll
    for (int mf = 0; mf < 4; ++mf) { ra[mf][0] = rdA(Ac, mf + 4, 0); ra[mf][1] = rdA(Ac, mf + 4, 1); }
    asm volatile("s_waitcnt lgkmcnt(0)" ::: "memory");
    __builtin_amdgcn_sched_barrier(0);
    __builtin_amdgcn_s_barrier();
    __builtin_amdgcn_s_setprio(1);
#pragma unroll
    for (int mf = 0; mf < 4; ++mf)
#pragma unroll
      for (int nf = 0; nf < 2; ++nf) {
        acc[mf + 4][nf] = mfma16(ra[mf][0], rb[nf][0], acc[mf + 4][nf]);
        acc[mf + 4][nf] = mfma16(ra[mf][1], rb[nf][1], acc[mf + 4][nf]);
      }
    __builtin_amdgcn_s_setprio(0);

    // ---- phase 3: stage A(kt+2) into A-cur (safe after ph2 barrier); vmcnt; barrier; MFMA
    if (kt + 2 < NK) { stage(Ap, m0, k2, Ac, 0); stage(Ap, m0, k2, Ac, 1); }
    if (kt + 2 < NK)
      asm volatile("s_waitcnt vmcnt(4)" ::: "memory");
    else
      asm volatile("s_waitcnt vmcnt(0)" ::: "memory");
    __builtin_amdgcn_sched_barrier(0);
    __builtin_amdgcn_s_barrier();
    __builtin_amdgcn_s_setprio(1);
#pragma unroll
    for (int mf = 0; mf < 4; ++mf)
#pragma unroll
      for (int nf = 2; nf < 4; ++nf) {
        acc[mf + 4][nf] = mfma16(ra[mf][0], rb[nf][0], acc[mf + 4][nf]);
        acc[mf + 4][nf] = mfma16(ra[mf][1], rb[nf][1], acc[mf + 4][nf]);
      }
    __builtin_amdgcn_s_setprio(0);
  }

  if (isQ) {
#pragma unroll
    for (int mf = 0; mf < 8; ++mf) {
      const int grow0 = m0 + wr * 128 + mf * 16 + 4 * lg;
#pragma unroll
      for (int nf = 0; nf < 4; ++nf) {
        const int gcol = n0 + wc * 64 + nf * 16 + lr;
        const int h = gcol >> 6, d = gcol & 63;
#pragma unroll
        for (int r = 0; r < 4; ++r) {
          const int grow = grow0 + r;
          const int b = grow >> 6, i = grow & 63;
          Qout[((size_t)((b * 16 + h) * 64 + i)) * 64 + d] = (bf16)acc[mf][nf][r];
        }
      }
    }
    return;
  }
#pragma unroll
  for (int mf = 0; mf < 8; ++mf) {
    const int grow0 = m0 + wr * 128 + mf * 16 + 4 * lg;
#pragma unroll
    for (int nf = 0; nf < 4; ++nf) {
      const int gcol = n0 + wc * 64 + nf * 16 + lr;
      if (gcol < 1024) {
        const int h = gcol >> 6, d = gcol & 63;
#pragma unroll
        for (int r = 0; r < 4; ++r) {
          const int grow = grow0 + r;
          const int bb = grow / 4160, s = grow % 4160;
          Kout[((size_t)((bb * 16 + h) * 4160 + s)) * 64 + d] = (bf16)acc[mf][nf][r];
        }
      } else {
        const int c2 = gcol - 1024, h = c2 >> 6, d = c2 & 63;
        const int bb = grow0 / 4160, s0 = grow0 % 4160;
        ushort4 u;
        u.x = bfbits(acc[mf][nf][0]);
        u.y = bfbits(acc[mf][nf][1]);
        u.z = bfbits(acc[mf][nf][2]);
        u.w = bfbits(acc[mf][nf][3]);
        *(ushort4*)&Vout[((size_t)((bb * 16 + h) * 64 + d)) * 4160 + s0] = u;
      }
    }
  }
}

// ---------------- flash attention partials: 4 independent waves/WG, 5 kv-chunks ----------------
__global__ __launch_bounds__(256) void attn_part(const bf16* __restrict__ qb_,
                                                 const bf16* __restrict__ kb_,
                                                 const bf16* __restrict__ vb_,
                                                 float* __restrict__ ob,
                                                 float* __restrict__ mb,
                                                 float* __restrict__ lb) {
  const int c = blockIdx.x;   // 0..4
  const int bh = blockIdx.y;  // 0..127
  const int tid = threadIdx.x;
  const int wave = tid >> 6, l = tid & 63;
  const int lg = l >> 4, lr = l & 15;
  const int qr0 = wave * 16;

  const bf16* q = qb_ + ((size_t)bh * 64 + qr0) * 64;
  const bf16* Kp = kb_ + (size_t)bh * 4160 * 64;
  const bf16* Vt = vb_ + (size_t)bh * 64 * 4160;

  bf16x8_t qf[2];
#pragma unroll
  for (int kk = 0; kk < 2; ++kk)
    qf[kk] = *(const bf16x8_t*)(q + lr * 64 + kk * 32 + lg * 8);

  f32x4_t oacc[4];
  float m[4], lsum[4];
#pragma unroll
  for (int r = 0; r < 4; ++r) { m[r] = -1e30f; lsum[r] = 0.f; }
#pragma unroll
  for (int nf = 0; nf < 4; ++nf) oacc[nf] = f32x4_t{0.f, 0.f, 0.f, 0.f};

  __shared__ bf16 plds[4][16][72];
  bf16(*P)[72] = plds[wave];

  constexpr float inv = 1.0f / 64.0f;

  bf16x8_t kf[2][4];
  auto ldK = [&](int key0) {
#pragma unroll
    for (int kk = 0; kk < 2; ++kk)
#pragma unroll
      for (int nf = 0; nf < 4; ++nf)
        kf[kk][nf] = *(const bf16x8_t*)(Kp + (size_t)(key0 + nf * 16 + lr) * 64 + kk * 32 + lg * 8);
  };

  ldK(c * 832);
  for (int kt = 0; kt < 13; ++kt) {
    const int key0 = c * 832 + kt * 64;
    f32x4_t sf[4];
#pragma unroll
    for (int nf = 0; nf < 4; ++nf) sf[nf] = f32x4_t{0.f, 0.f, 0.f, 0.f};
#pragma unroll
    for (int kk = 0; kk < 2; ++kk)
#pragma unroll
      for (int nf = 0; nf < 4; ++nf)
        sf[nf] = mfma16(qf[kk], kf[kk][nf], sf[nf]);
    if (kt + 1 < 13) ldK(key0 + 64);
    float corr[4];
#pragma unroll
    for (int r = 0; r < 4; ++r) {
      float t = fmaxf(fmaxf(sf[0][r], sf[1][r]), fmaxf(sf[2][r], sf[3][r])) * inv;
#pragma unroll
      for (int off = 1; off < 16; off <<= 1) t = fmaxf(t, __shfl_xor(t, off));
      const float mn = fmaxf(t, m[r]);
      corr[r] = __expf(m[r] - mn);
      m[r] = mn;
    }
    float rowsum[4] = {0.f, 0.f, 0.f, 0.f};
#pragma unroll
    for (int nf = 0; nf < 4; ++nf)
#pragma unroll
      for (int r = 0; r < 4; ++r) {
        const float p = __expf(sf[nf][r] * inv - m[r]);
        rowsum[r] += p;
        P[lg * 4 + r][nf * 16 + lr] = (bf16)p;
      }
#pragma unroll
    for (int r = 0; r < 4; ++r) {
      float t = rowsum[r];
#pragma unroll
      for (int off = 1; off < 16; off <<= 1) t += __shfl_xor(t, off);
      lsum[r] = lsum[r] * corr[r] + t;
    }
#pragma unroll
    for (int nf = 0; nf < 4; ++nf) {
      oacc[nf][0] *= corr[0];
      oacc[nf][1] *= corr[1];
      oacc[nf][2] *= corr[2];
      oacc[nf][3] *= corr[3];
    }
    bf16x8_t vf[2][4];
#pragma unroll
    for (int kk = 0; kk < 2; ++kk)
#pragma unroll
      for (int nf = 0; nf < 4; ++nf)
        vf[kk][nf] = *(const bf16x8_t*)(Vt + (size_t)(nf * 16 + lr) * 4160 + key0 + kk * 32 + lg * 8);
    asm volatile("s_waitcnt lgkmcnt(0)" ::: "memory");
#pragma unroll
    for (int kk = 0; kk < 2; ++kk) {
      bf16x8_t pf = *(const bf16x8_t*)&P[lr][kk * 32 + lg * 8];
#pragma unroll
      for (int nf = 0; nf < 4; ++nf)
        oacc[nf] = mfma16(pf, vf[kk][nf], oacc[nf]);
    }
    asm volatile("s_waitcnt lgkmcnt(0)" ::: "memory");
  }

#pragma unroll
  for (int nf = 0; nf < 4; ++nf)
#pragma unroll
    for (int r = 0; r < 4; ++r) {
      const int i = qr0 + lg * 4 + r;
      ob[((size_t)((bh * 64 + i) * 5 + c)) * 64 + nf * 16 + lr] = oacc[nf][r];
    }
  if (lr == 0) {
#pragma unroll
    for (int r = 0; r < 4; ++r) {
      const int i = qr0 + lg * 4 + r;
      mb[(bh * 64 + i) * 5 + c] = m[r];
      lb[(bh * 64 + i) * 5 + c] = lsum[r];
    }
  }
}

// ---------------- merge partials -> aout[b*64+i][h*64+d] bf16 ----------------
__global__ __launch_bounds__(256) void attn_merge(const float* __restrict__ ob,
                                                  const float* __restrict__ mb,
                                                  const float* __restrict__ lb,
                                                  bf16* __restrict__ aout) {
  const int j = blockIdx.x * 4 + (threadIdx.x >> 6);  // row 0..8191
  const int l = threadIdx.x & 63;
  float mv[5];
  float mx = -1e30f;
#pragma unroll
  for (int cc = 0; cc < 5; ++cc) { mv[cc] = mb[j * 5 + cc]; mx = fmaxf(mx, mv[cc]); }
  float L = 0.f, o = 0.f;
#pragma unroll
  for (int cc = 0; cc < 5; ++cc) {
    const float wgt = __expf(mv[cc] - mx);
    L += lb[j * 5 + cc] * wgt;
    o += wgt * ob[((size_t)(j * 5 + cc)) * 64 + l];
  }
  const int bh = j >> 6, i = j & 63, b = bh >> 4, h = bh & 15;
  aout[((size_t)(b * 64 + i)) * 1024 + h * 64 + l] = (bf16)(o / L);
}

// ---------------- launch ----------------
extern "C" void kernel_launch(void* const* d_in, const int* in_sizes, int n_in,
                              void* d_out, int out_size, void* d_ws, size_t ws_size,
                              hipStream_t stream) {
  (void)in_sizes; (void)n_in; (void)out_size; (void)ws_size;
  const float* x   = (const float*)d_in[0];
  const float* lat = (const float*)d_in[1];
  const float* g1  = (const float*)d_in[2];
  const float* b1  = (const float*)d_in[3];
  const float* g2  = (const float*)d_in[4];
  const float* b2  = (const float*)d_in[5];
  const float* Wq  = (const float*)d_in[6];
  const float* Wkv = (const float*)d_in[7];
  const float* Wo  = (const float*)d_in[8];
  float* out = (float*)d_out;

  char* ws = (char*)d_ws;
  size_t off = 0;
  auto alloc = [&](size_t bytes) {
    void* p = ws + off;
    off += (bytes + 255) & ~(size_t)255;
    return p;
  };
  bf16* kv_in = (bf16*)alloc(8ull * 4160 * 1024 * 2);     // concat(xn, ln) rows
  bf16* Wkv_t = (bf16*)alloc(2048ull * 1024 * 2);
  bf16* Wq_t  = (bf16*)alloc(1024ull * 1024 * 2);
  bf16* Wo_t  = (bf16*)alloc(1024ull * 1024 * 2);
  bf16* lnq   = (bf16*)alloc(512ull * 1024 * 2);
  bf16* qbuf  = (bf16*)alloc(512ull * 1024 * 2);          // [b,h,i,d]
  bf16* kbuf  = (bf16*)alloc(8ull * 16 * 4160 * 64 * 2);  // [b,h,s,d]
  bf16* vtbuf = (bf16*)alloc(8ull * 16 * 4160 * 64 * 2);  // [b,h,d,s]
  bf16* aout  = (bf16*)alloc(512ull * 1024 * 2);          // [b*64+i, h*64+d]

  // attention partials aliased into kv_in (dead after gemm256_kv)
  float* obuf = (float*)kv_in;           // 8192 * 5 * 64 f32
  float* mbuf = obuf + 8192ull * 5 * 64; // 8192 * 5
  float* lbuf = mbuf + 8192ull * 5;

  (void)hipFuncSetAttribute(reinterpret_cast<const void*>(gemm256_kv),
                            hipFuncAttributeMaxDynamicSharedMemorySize, 131072);

  prep_all<<<12416, 256, 0, stream>>>(x, lat, g1, b1, g2, b2, Wq, Wkv, Wo,
                                      kv_in, lnq, Wq_t, Wkv_t, Wo_t);

  gemm256_kv<<<1048, 512, 131072, stream>>>(kv_in, lnq, Wkv_t, Wq_t, kbuf, vtbuf, qbuf);

  attn_part<<<dim3(5, 128), 256, 0, stream>>>(qbuf, kbuf, vtbuf, obuf, mbuf, lbuf);
  attn_merge<<<2048, 256, 0, stream>>>(obuf, mbuf, lbuf, aout);

  (void)hipMemsetAsync(out, 0, 512ull * 1024 * 4, stream);
  gemm_bt_sk<<<dim3(8, 4, 4), 256, 0, stream>>>(aout, Wo_t, out);
}

// Round 11
// 273.192 us; speedup vs baseline: 6.0947x; 1.0413x over previous
//
#include <hip/hip_runtime.h>

typedef __bf16 bf16;
typedef bf16 bf16x4_t __attribute__((ext_vector_type(4)));
typedef bf16 bf16x8_t __attribute__((ext_vector_type(8)));
typedef float f32x4_t __attribute__((ext_vector_type(4)));

#define DI __device__ __forceinline__

DI void gload_lds16(const void* g, void* l) {
  __builtin_amdgcn_global_load_lds((const __attribute__((address_space(1))) void*)g,
                                   (__attribute__((address_space(3))) void*)l, 16, 0, 0);
}

DI f32x4_t mfma16(bf16x8_t a, bf16x8_t b, f32x4_t c) {
  return __builtin_amdgcn_mfma_f32_16x16x32_bf16(a, b, c, 0, 0, 0);
}

DI unsigned short bfbits(float f) {
  bf16 h = (bf16)f;
  return __builtin_bit_cast(unsigned short, h);
}

// ---------------- fused prep: LN (1 wave/row) + weight transposes ----------------
__global__ __launch_bounds__(256) void prep_all(const float* __restrict__ x,
                                                const float* __restrict__ lat,
                                                const float* __restrict__ g1,
                                                const float* __restrict__ b1,
                                                const float* __restrict__ g2,
                                                const float* __restrict__ b2,
                                                const float* __restrict__ Wq,
                                                const float* __restrict__ Wkv,
                                                const float* __restrict__ Wo,
                                                bf16* __restrict__ kv_in,
                                                bf16* __restrict__ lnq,
                                                bf16* __restrict__ Wq_t,
                                                bf16* __restrict__ Wkv_t,
                                                bf16* __restrict__ Wo_t) {
  const int bid = blockIdx.x;
  const int t = threadIdx.x;
  if (bid < 8320) {
    const int wv = t >> 6, l = t & 63;
    const int row = bid * 4 + wv;
    const float* in;
    const float* gamma;
    const float* beta;
    size_t orow;
    bool dual = false;
    int lrow = 0;
    if (row < 32768) {
      in = x + (size_t)row * 1024;
      gamma = g1; beta = b1;
      orow = (size_t)(row >> 12) * 4160 + (row & 4095);
    } else {
      const int r = row - 32768;
      in = lat + (size_t)r * 1024;
      gamma = g2; beta = b2;
      orow = (size_t)(r >> 6) * 4160 + 4096 + (r & 63);
      dual = true;
      lrow = r;
    }
    float4 v[4];
    float s = 0.f, q = 0.f;
#pragma unroll
    for (int i = 0; i < 4; ++i) {
      v[i] = ((const float4*)in)[i * 64 + l];
      s += v[i].x + v[i].y + v[i].z + v[i].w;
      q += v[i].x * v[i].x + v[i].y * v[i].y + v[i].z * v[i].z + v[i].w * v[i].w;
    }
#pragma unroll
    for (int off = 1; off < 64; off <<= 1) {
      s += __shfl_xor(s, off);
      q += __shfl_xor(q, off);
    }
    const float mu = s * (1.f / 1024.f);
    const float var = q * (1.f / 1024.f) - mu * mu;
    const float rs = rsqrtf(var + 1e-5f);
#pragma unroll
    for (int i = 0; i < 4; ++i) {
      const float4 gv = ((const float4*)gamma)[i * 64 + l];
      const float4 bv = ((const float4*)beta)[i * 64 + l];
      bf16x4_t o;
      o[0] = (bf16)((v[i].x - mu) * rs * gv.x + bv.x);
      o[1] = (bf16)((v[i].y - mu) * rs * gv.y + bv.y);
      o[2] = (bf16)((v[i].z - mu) * rs * gv.z + bv.z);
      o[3] = (bf16)((v[i].w - mu) * rs * gv.w + bv.w);
      *(bf16x4_t*)(kv_in + orow * 1024 + i * 256 + l * 4) = o;
      if (dual) *(bf16x4_t*)(lnq + (size_t)lrow * 1024 + i * 256 + l * 4) = o;
    }
  } else {
    __shared__ float tile[32][33];
    const int b2i = bid - 8320;
    const float* W;
    bf16* Wt;
    int C, t0;
    if (b2i < 1024)      { W = Wq;  Wt = Wq_t;  C = 1024; t0 = b2i; }
    else if (b2i < 3072) { W = Wkv; Wt = Wkv_t; C = 2048; t0 = b2i - 1024; }
    else                 { W = Wo;  Wt = Wo_t;  C = 1024; t0 = b2i - 3072; }
    const int R = 1024;
    const int ntx = C >> 5;
    const int c0 = (t0 % ntx) * 32, r0 = (t0 / ntx) * 32;
    const int tx = t & 31, ty = t >> 5;
#pragma unroll
    for (int j = 0; j < 4; ++j)
      tile[ty + j * 8][tx] = W[(size_t)(r0 + ty + j * 8) * C + c0 + tx];
    __syncthreads();
#pragma unroll
    for (int j = 0; j < 4; ++j)
      Wt[(size_t)(c0 + ty + j * 8) * R + r0 + tx] = (bf16)tile[tx][ty + j * 8];
  }
}

// ---------------- out GEMM, split-K=4, atomic f32 accumulate ----------------
__global__ __launch_bounds__(256) void gemm_bt_sk(const bf16* __restrict__ A,
                                                  const bf16* __restrict__ Bt,
                                                  float* __restrict__ Cf) {
  __shared__ bf16 As[128 * 32];
  __shared__ bf16 Bs[128 * 32];
  const int tid = threadIdx.x;
  const int w = tid >> 6, l = tid & 63;
  const int lg = l >> 4, lr = l & 15;
  const int m0 = blockIdx.y * 128, n0 = blockIdx.x * 128;
  const int kbase = blockIdx.z * 256;
  const int wm = w >> 1, wn = w & 1;
  const int K = 1024, N = 1024;

  f32x4_t acc[4][4];
#pragma unroll
  for (int i = 0; i < 4; ++i)
#pragma unroll
    for (int j = 0; j < 4; ++j)
      acc[i][j] = f32x4_t{0.f, 0.f, 0.f, 0.f};

  for (int kt = 0; kt < 8; ++kt) {
    const int k0 = kbase + kt * 32;
#pragma unroll
    for (int j = 0; j < 2; ++j) {
      const int rb = j * 64 + w * 16;
      const int r = rb + (l >> 2);
      const int c = (l & 3) * 8;
      gload_lds16(A + (size_t)(m0 + r) * K + k0 + c, &As[rb * 32]);
      gload_lds16(Bt + (size_t)(n0 + r) * K + k0 + c, &Bs[rb * 32]);
    }
    __syncthreads();
    bf16x8_t af[4], bfr[4];
#pragma unroll
    for (int i = 0; i < 4; ++i) {
      af[i] = *(const bf16x8_t*)&As[(wm * 64 + i * 16 + lr) * 32 + lg * 8];
      bfr[i] = *(const bf16x8_t*)&Bs[(wn * 64 + i * 16 + lr) * 32 + lg * 8];
    }
#pragma unroll
    for (int mf = 0; mf < 4; ++mf)
#pragma unroll
      for (int nf = 0; nf < 4; ++nf)
        acc[mf][nf] = mfma16(af[mf], bfr[nf], acc[mf][nf]);
    __syncthreads();
  }

#pragma unroll
  for (int mf = 0; mf < 4; ++mf)
#pragma unroll
    for (int r = 0; r < 4; ++r) {
      const int grow = m0 + wm * 64 + mf * 16 + 4 * lg + r;
#pragma unroll
      for (int nf = 0; nf < 4; ++nf) {
        const int gcol = n0 + wn * 64 + nf * 16 + lr;
        unsafeAtomicAdd(&Cf[(size_t)grow * N + gcol], acc[mf][nf][r]);
      }
    }
}

// ---------------- templated 4-phase GEMM body: (MF*32)x256 tile ----------------
// MF=8: 256-row tile (acc 128 AGPR).  MF=4: 128-row half tile (tail, acc 64 AGPR).
// Double-buffered swizzled LDS; ONE barrier per phase. B staged 1 tile ahead
// (ph0/ph1 -> nxt buf), A staged 2 ahead (ph3 -> cur buf, safe after ph2 drain).
// vmcnt(MF/2) once/tile leaves A(kt+2) in flight.
template<int MF>
DI void gemm_body(const bf16* __restrict__ Ap, const bf16* __restrict__ Bp,
                  int m0, int n0, int mode,  // mode 0 = kv scatter, 1 = q scatter
                  bf16* __restrict__ Kout, bf16* __restrict__ Vout,
                  bf16* __restrict__ Qout, char* lds,
                  int w, int l, int lr, int lg, int wr, int wc) {
  constexpr int ABYTES = MF * 32 * 128;  // A tile bytes (rows * 128B)
  constexpr int AU = MF / 2;             // A stage units (64 rows each)

  auto stageU = [&](const bf16* __restrict__ G, int row0, int k0, char* base, int unit) {
    const int r0 = unit * 64 + w * 8;
    const int row = r0 + (l >> 3);
    const int col = ((l & 7) ^ (l >> 3)) * 8;
    gload_lds16(G + (size_t)(row0 + row) * 1024 + k0 + col, base + r0 * 128);
  };
  auto rdA = [&](char* base, int mf, int ks) -> bf16x8_t {
    const int row = wr * (MF * 16) + mf * 16 + lr;
    int byte = row * 128 + (ks * 32 + lg * 8) * 2;
    byte ^= (row & 7) << 4;
    return *(const bf16x8_t*)(base + byte);
  };
  auto rdB = [&](char* base, int nf, int ks) -> bf16x8_t {
    const int row = wc * 64 + nf * 16 + lr;
    int byte = row * 128 + (ks * 32 + lg * 8) * 2;
    byte ^= (row & 7) << 4;
    return *(const bf16x8_t*)(base + byte);
  };

  f32x4_t acc[MF][4];
#pragma unroll
  for (int i = 0; i < MF; ++i)
#pragma unroll
    for (int j = 0; j < 4; ++j)
      acc[i][j] = f32x4_t{0.f, 0.f, 0.f, 0.f};

  const int NK = 16;

  // prologue: A(0), B(0), A(1) — oldest-first so vmcnt(AU) drains A(0)+B(0)
#pragma unroll
  for (int u = 0; u < AU; ++u) stageU(Ap, m0, 0, lds, u);
#pragma unroll
  for (int u = 0; u < 4; ++u) stageU(Bp, n0, 0, lds + ABYTES, u);
#pragma unroll
  for (int u = 0; u < AU; ++u) stageU(Ap, m0, 64, lds + ABYTES + 32768, u);
  if constexpr (MF == 8) asm volatile("s_waitcnt vmcnt(4)" ::: "memory");
  else                   asm volatile("s_waitcnt vmcnt(2)" ::: "memory");
  __builtin_amdgcn_s_barrier();

  bf16x8_t ra[AU][2], rb[4][2];
  for (int kt = 0; kt < NK; ++kt) {
    const int cur = kt & 1, nxt = cur ^ 1;
    char* Ac = lds + cur * (ABYTES + 32768);
    char* Bc = Ac + ABYTES;
    char* Bn = lds + nxt * (ABYTES + 32768) + ABYTES;
    const int k1 = (kt + 1) << 6, k2 = (kt + 2) << 6;

    // ---- phase 0: reads A lower + B nf0-1; stage B units 0-1 (kt+1); 1 barrier; MFMA
#pragma unroll
    for (int mf = 0; mf < AU; ++mf) { ra[mf][0] = rdA(Ac, mf, 0); ra[mf][1] = rdA(Ac, mf, 1); }
#pragma unroll
    for (int nf = 0; nf < 2; ++nf) { rb[nf][0] = rdB(Bc, nf, 0); rb[nf][1] = rdB(Bc, nf, 1); }
    if (kt + 1 < NK) { stageU(Bp, n0, k1, Bn, 0); stageU(Bp, n0, k1, Bn, 1); }
    asm volatile("s_waitcnt lgkmcnt(0)" ::: "memory");
    __builtin_amdgcn_sched_barrier(0);
    __builtin_amdgcn_s_barrier();
    __builtin_amdgcn_s_setprio(1);
#pragma unroll
    for (int mf = 0; mf < AU; ++mf)
#pragma unroll
      for (int nf = 0; nf < 2; ++nf) {
        acc[mf][nf] = mfma16(ra[mf][0], rb[nf][0], acc[mf][nf]);
        acc[mf][nf] = mfma16(ra[mf][1], rb[nf][1], acc[mf][nf]);
      }
    __builtin_amdgcn_s_setprio(0);

    // ---- phase 1: reads B nf2-3; stage B units 2-3 (kt+1); 1 barrier; MFMA
#pragma unroll
    for (int nf = 2; nf < 4; ++nf) { rb[nf][0] = rdB(Bc, nf, 0); rb[nf][1] = rdB(Bc, nf, 1); }
    if (kt + 1 < NK) { stageU(Bp, n0, k1, Bn, 2); stageU(Bp, n0, k1, Bn, 3); }
    asm volatile("s_waitcnt lgkmcnt(0)" ::: "memory");
    __builtin_amdgcn_sched_barrier(0);
    __builtin_amdgcn_s_barrier();
    __builtin_amdgcn_s_setprio(1);
#pragma unroll
    for (int mf = 0; mf < AU; ++mf)
#pragma unroll
      for (int nf = 2; nf < 4; ++nf) {
        acc[mf][nf] = mfma16(ra[mf][0], rb[nf][0], acc[mf][nf]);
        acc[mf][nf] = mfma16(ra[mf][1], rb[nf][1], acc[mf][nf]);
      }
    __builtin_amdgcn_s_setprio(0);

    // ---- phase 2: reads A upper; 1 barrier; MFMA (all A-cur reads drained here)
#pragma unroll
    for (int mf = 0; mf < AU; ++mf) { ra[mf][0] = rdA(Ac, mf + AU, 0); ra[mf][1] = rdA(Ac, mf + AU, 1); }
    asm volatile("s_waitcnt lgkmcnt(0)" ::: "memory");
    __builtin_amdgcn_sched_barrier(0);
    __builtin_amdgcn_s_barrier();
    __builtin_amdgcn_s_setprio(1);
#pragma unroll
    for (int mf = 0; mf < AU; ++mf)
#pragma unroll
      for (int nf = 0; nf < 2; ++nf) {
        acc[mf + AU][nf] = mfma16(ra[mf][0], rb[nf][0], acc[mf + AU][nf]);
        acc[mf + AU][nf] = mfma16(ra[mf][1], rb[nf][1], acc[mf + AU][nf]);
      }
    __builtin_amdgcn_s_setprio(0);

    // ---- phase 3: stage A(kt+2) into A-cur (safe after ph2 barrier); vmcnt; barrier; MFMA
    if (kt + 2 < NK) {
#pragma unroll
      for (int u = 0; u < AU; ++u) stageU(Ap, m0, k2, Ac, u);
      if constexpr (MF == 8) asm volatile("s_waitcnt vmcnt(4)" ::: "memory");
      else                   asm volatile("s_waitcnt vmcnt(2)" ::: "memory");
    } else {
      asm volatile("s_waitcnt vmcnt(0)" ::: "memory");
    }
    __builtin_amdgcn_sched_barrier(0);
    __builtin_amdgcn_s_barrier();
    __builtin_amdgcn_s_setprio(1);
#pragma unroll
    for (int mf = 0; mf < AU; ++mf)
#pragma unroll
      for (int nf = 2; nf < 4; ++nf) {
        acc[mf + AU][nf] = mfma16(ra[mf][0], rb[nf][0], acc[mf + AU][nf]);
        acc[mf + AU][nf] = mfma16(ra[mf][1], rb[nf][1], acc[mf + AU][nf]);
      }
    __builtin_amdgcn_s_setprio(0);
  }

  if (mode == 1) {
#pragma unroll
    for (int mf = 0; mf < MF; ++mf) {
      const int grow0 = m0 + wr * (MF * 16) + mf * 16 + 4 * lg;
#pragma unroll
      for (int nf = 0; nf < 4; ++nf) {
        const int gcol = n0 + wc * 64 + nf * 16 + lr;
        const int h = gcol >> 6, d = gcol & 63;
#pragma unroll
        for (int r = 0; r < 4; ++r) {
          const int grow = grow0 + r;
          const int b = grow >> 6, i = grow & 63;
          Qout[((size_t)((b * 16 + h) * 64 + i)) * 64 + d] = (bf16)acc[mf][nf][r];
        }
      }
    }
    return;
  }
#pragma unroll
  for (int mf = 0; mf < MF; ++mf) {
    const int grow0 = m0 + wr * (MF * 16) + mf * 16 + 4 * lg;
#pragma unroll
    for (int nf = 0; nf < 4; ++nf) {
      const int gcol = n0 + wc * 64 + nf * 16 + lr;
      if (gcol < 1024) {  // K half: k[b,h,s,d]
        const int h = gcol >> 6, d = gcol & 63;
#pragma unroll
        for (int r = 0; r < 4; ++r) {
          const int grow = grow0 + r;
          const int bb = grow / 4160, s = grow % 4160;
          Kout[((size_t)((bb * 16 + h) * 4160 + s)) * 64 + d] = (bf16)acc[mf][nf][r];
        }
      } else {  // V half: v^T[b,h,d,s], pack 4 consecutive s
        const int c2 = gcol - 1024, h = c2 >> 6, d = c2 & 63;
        const int bb = grow0 / 4160, s0 = grow0 % 4160;
        ushort4 u;
        u.x = bfbits(acc[mf][nf][0]);
        u.y = bfbits(acc[mf][nf][1]);
        u.z = bfbits(acc[mf][nf][2]);
        u.w = bfbits(acc[mf][nf][3]);
        *(ushort4*)&Vout[((size_t)((bb * 16 + h) * 64 + d)) * 4160 + s0] = u;
      }
    }
  }
}

// ---------------- GEMM dispatcher: 1024 full tiles + 48 half-M tail tiles ----------------
// bid<1024 (XCD-swizzled): swz<1016 -> kv tile tm=swz/8 (tm 0..126); swz>=1016 -> q tile.
// bid>=1024: 48 half-M tiles covering kv tm 127..129 (rows 32512..33279), dispatched
// LAST so the makespan tail is ~0.55T instead of T (uniform-length tail quantization fix).
__global__ __launch_bounds__(512, 2) void gemm256_kv(const bf16* __restrict__ Akv,
                                                     const bf16* __restrict__ Aq,
                                                     const bf16* __restrict__ BtKV,
                                                     const bf16* __restrict__ BtQ,
                                                     bf16* __restrict__ Kout,
                                                     bf16* __restrict__ Vout,
                                                     bf16* __restrict__ Qout) {
  extern __shared__ char lds[];
  const int tid = threadIdx.x;
  const int w = tid >> 6, l = tid & 63;
  const int lr = l & 15, lg = l >> 4;
  const int wr = w >> 2, wc = w & 3;
  const int bid = blockIdx.x;

  if (bid < 1024) {
    const int swz = (bid & 7) * 128 + (bid >> 3);
    if (swz < 1016) {
      const int m0 = (swz >> 3) << 8, n0 = (swz & 7) << 8;
      gemm_body<8>(Akv, BtKV, m0, n0, 0, Kout, Vout, Qout, lds, w, l, lr, lg, wr, wc);
    } else {
      const int qi = swz - 1016;
      const int m0 = (qi >> 2) << 8, n0 = (qi & 3) << 8;
      gemm_body<8>(Aq, BtQ, m0, n0, 1, Kout, Vout, Qout, lds, w, l, lr, lg, wr, wc);
    }
  } else {
    const int h2 = bid - 1024;          // 0..47
    const int t = h2 >> 1;              // 0..23
    const int tm = 127 + t / 8, tn = t % 8;
    const int m0 = tm * 256 + (h2 & 1) * 128;
    gemm_body<4>(Akv, BtKV, m0, tn << 8, 0, Kout, Vout, Qout, lds, w, l, lr, lg, wr, wc);
  }
}

// ---------------- flash attention partials: 4 independent waves/WG, 5 kv-chunks ----------------
__global__ __launch_bounds__(256) void attn_part(const bf16* __restrict__ qb_,
                                                 const bf16* __restrict__ kb_,
                                                 const bf16* __restrict__ vb_,
                                                 float* __restrict__ ob,
                                                 float* __restrict__ mb,
                                                 float* __restrict__ lb) {
  const int c = blockIdx.x;   // 0..4
  const int bh = blockIdx.y;  // 0..127
  const int tid = threadIdx.x;
  const int wave = tid >> 6, l = tid & 63;
  const int lg = l >> 4, lr = l & 15;
  const int qr0 = wave * 16;

  const bf16* q = qb_ + ((size_t)bh * 64 + qr0) * 64;
  const bf16* Kp = kb_ + (size_t)bh * 4160 * 64;
  const bf16* Vt = vb_ + (size_t)bh * 64 * 4160;

  bf16x8_t qf[2];
#pragma unroll
  for (int kk = 0; kk < 2; ++kk)
    qf[kk] = *(const bf16x8_t*)(q + lr * 64 + kk * 32 + lg * 8);

  f32x4_t oacc[4];
  float m[4], lsum[4];
#pragma unroll
  for (int r = 0; r < 4; ++r) { m[r] = -1e30f; lsum[r] = 0.f; }
#pragma unroll
  for (int nf = 0; nf < 4; ++nf) oacc[nf] = f32x4_t{0.f, 0.f, 0.f, 0.f};

  __shared__ bf16 plds[4][16][72];
  bf16(*P)[72] = plds[wave];

  constexpr float inv = 1.0f / 64.0f;

  bf16x8_t kf[2][4];
  auto ldK = [&](int key0) {
#pragma unroll
    for (int kk = 0; kk < 2; ++kk)
#pragma unroll
      for (int nf = 0; nf < 4; ++nf)
        kf[kk][nf] = *(const bf16x8_t*)(Kp + (size_t)(key0 + nf * 16 + lr) * 64 + kk * 32 + lg * 8);
  };

  ldK(c * 832);
  for (int kt = 0; kt < 13; ++kt) {
    const int key0 = c * 832 + kt * 64;
    f32x4_t sf[4];
#pragma unroll
    for (int nf = 0; nf < 4; ++nf) sf[nf] = f32x4_t{0.f, 0.f, 0.f, 0.f};
#pragma unroll
    for (int kk = 0; kk < 2; ++kk)
#pragma unroll
      for (int nf = 0; nf < 4; ++nf)
        sf[nf] = mfma16(qf[kk], kf[kk][nf], sf[nf]);
    if (kt + 1 < 13) ldK(key0 + 64);
    float corr[4];
#pragma unroll
    for (int r = 0; r < 4; ++r) {
      float t = fmaxf(fmaxf(sf[0][r], sf[1][r]), fmaxf(sf[2][r], sf[3][r])) * inv;
#pragma unroll
      for (int off = 1; off < 16; off <<= 1) t = fmaxf(t, __shfl_xor(t, off));
      const float mn = fmaxf(t, m[r]);
      corr[r] = __expf(m[r] - mn);
      m[r] = mn;
    }
    float rowsum[4] = {0.f, 0.f, 0.f, 0.f};
#pragma unroll
    for (int nf = 0; nf < 4; ++nf)
#pragma unroll
      for (int r = 0; r < 4; ++r) {
        const float p = __expf(sf[nf][r] * inv - m[r]);
        rowsum[r] += p;
        P[lg * 4 + r][nf * 16 + lr] = (bf16)p;
      }
#pragma unroll
    for (int r = 0; r < 4; ++r) {
      float t = rowsum[r];
#pragma unroll
      for (int off = 1; off < 16; off <<= 1) t += __shfl_xor(t, off);
      lsum[r] = lsum[r] * corr[r] + t;
    }
#pragma unroll
    for (int nf = 0; nf < 4; ++nf) {
      oacc[nf][0] *= corr[0];
      oacc[nf][1] *= corr[1];
      oacc[nf][2] *= corr[2];
      oacc[nf][3] *= corr[3];
    }
    bf16x8_t vf[2][4];
#pragma unroll
    for (int kk = 0; kk < 2; ++kk)
#pragma unroll
      for (int nf = 0; nf < 4; ++nf)
        vf[kk][nf] = *(const bf16x8_t*)(Vt + (size_t)(nf * 16 + lr) * 4160 + key0 + kk * 32 + lg * 8);
    asm volatile("s_waitcnt lgkmcnt(0)" ::: "memory");
#pragma unroll
    for (int kk = 0; kk < 2; ++kk) {
      bf16x8_t pf = *(const bf16x8_t*)&P[lr][kk * 32 + lg * 8];
#pragma unroll
      for (int nf = 0; nf < 4; ++nf)
        oacc[nf] = mfma16(pf, vf[kk][nf], oacc[nf]);
    }
    asm volatile("s_waitcnt lgkmcnt(0)" ::: "memory");
  }

#pragma unroll
  for (int nf = 0; nf < 4; ++nf)
#pragma unroll
    for (int r = 0; r < 4; ++r) {
      const int i = qr0 + lg * 4 + r;
      ob[((size_t)((bh * 64 + i) * 5 + c)) * 64 + nf * 16 + lr] = oacc[nf][r];
    }
  if (lr == 0) {
#pragma unroll
    for (int r = 0; r < 4; ++r) {
      const int i = qr0 + lg * 4 + r;
      mb[(bh * 64 + i) * 5 + c] = m[r];
      lb[(bh * 64 + i) * 5 + c] = lsum[r];
    }
  }
}

// ---------------- merge partials -> aout; also zero the final-output accumulator ----------------
__global__ __launch_bounds__(256) void attn_merge(const float* __restrict__ ob,
                                                  const float* __restrict__ mb,
                                                  const float* __restrict__ lb,
                                                  bf16* __restrict__ aout,
                                                  float* __restrict__ outz) {
  // zero final out (512*1024 f32 == grid*block threads, 1:1) — replaces hipMemsetAsync
  outz[(size_t)blockIdx.x * 256 + threadIdx.x] = 0.f;

  const int j = blockIdx.x * 4 + (threadIdx.x >> 6);  // row 0..8191
  const int l = threadIdx.x & 63;
  float mv[5];
  float mx = -1e30f;
#pragma unroll
  for (int cc = 0; cc < 5; ++cc) { mv[cc] = mb[j * 5 + cc]; mx = fmaxf(mx, mv[cc]); }
  float L = 0.f, o = 0.f;
#pragma unroll
  for (int cc = 0; cc < 5; ++cc) {
    const float wgt = __expf(mv[cc] - mx);
    L += lb[j * 5 + cc] * wgt;
    o += wgt * ob[((size_t)(j * 5 + cc)) * 64 + l];
  }
  const int bh = j >> 6, i = j & 63, b = bh >> 4, h = bh & 15;
  aout[((size_t)(b * 64 + i)) * 1024 + h * 64 + l] = (bf16)(o / L);
}

// ---------------- launch ----------------
extern "C" void kernel_launch(void* const* d_in, const int* in_sizes, int n_in,
                              void* d_out, int out_size, void* d_ws, size_t ws_size,
                              hipStream_t stream) {
  (void)in_sizes; (void)n_in; (void)out_size; (void)ws_size;
  const float* x   = (const float*)d_in[0];
  const float* lat = (const float*)d_in[1];
  const float* g1  = (const float*)d_in[2];
  const float* b1  = (const float*)d_in[3];
  const float* g2  = (const float*)d_in[4];
  const float* b2  = (const float*)d_in[5];
  const float* Wq  = (const float*)d_in[6];
  const float* Wkv = (const float*)d_in[7];
  const float* Wo  = (const float*)d_in[8];
  float* out = (float*)d_out;

  char* ws = (char*)d_ws;
  size_t off = 0;
  auto alloc = [&](size_t bytes) {
    void* p = ws + off;
    off += (bytes + 255) & ~(size_t)255;
    return p;
  };
  bf16* kv_in = (bf16*)alloc(8ull * 4160 * 1024 * 2);     // concat(xn, ln) rows
  bf16* Wkv_t = (bf16*)alloc(2048ull * 1024 * 2);
  bf16* Wq_t  = (bf16*)alloc(1024ull * 1024 * 2);
  bf16* Wo_t  = (bf16*)alloc(1024ull * 1024 * 2);
  bf16* lnq   = (bf16*)alloc(512ull * 1024 * 2);
  bf16* qbuf  = (bf16*)alloc(512ull * 1024 * 2);          // [b,h,i,d]
  bf16* kbuf  = (bf16*)alloc(8ull * 16 * 4160 * 64 * 2);  // [b,h,s,d]
  bf16* vtbuf = (bf16*)alloc(8ull * 16 * 4160 * 64 * 2);  // [b,h,d,s]
  bf16* aout  = (bf16*)alloc(512ull * 1024 * 2);          // [b*64+i, h*64+d]

  // attention partials aliased into kv_in (dead after gemm256_kv)
  float* obuf = (float*)kv_in;           // 8192 * 5 * 64 f32
  float* mbuf = obuf + 8192ull * 5 * 64; // 8192 * 5
  float* lbuf = mbuf + 8192ull * 5;

  (void)hipFuncSetAttribute(reinterpret_cast<const void*>(gemm256_kv),
                            hipFuncAttributeMaxDynamicSharedMemorySize, 131072);

  prep_all<<<12416, 256, 0, stream>>>(x, lat, g1, b1, g2, b2, Wq, Wkv, Wo,
                                      kv_in, lnq, Wq_t, Wkv_t, Wo_t);

  gemm256_kv<<<1072, 512, 131072, stream>>>(kv_in, lnq, Wkv_t, Wq_t, kbuf, vtbuf, qbuf);

  attn_part<<<dim3(5, 128), 256, 0, stream>>>(qbuf, kbuf, vtbuf, obuf, mbuf, lbuf);
  attn_merge<<<2048, 256, 0, stream>>>(obuf, mbuf, lbuf, aout, out);

  gemm_bt_sk<<<dim3(8, 4, 4), 256, 0, stream>>>(aout, Wo_t, out);
}